// Round 3
// baseline (1361.020 us; speedup 1.0000x reference)
//
#include <hip/hip_runtime.h>
#include <cstdint>

#define NB 512     // batch
#define SS 128     // sequence
#define DIN 360    // emb(300)+pos(30)+ner(30)
#define DHID 300
#define DDEPW 100  // deprel embedding dim
#define NCLS 42

constexpr float INF_ = 1e12f;   // matches reference INF
constexpr float NEG_ = -1e30f;  // matches reference NEG

// ---------------- degrees / masks / denom ----------------
__global__ void k_degrees(const float* __restrict__ adj, float* __restrict__ denom,
                          int* __restrict__ pmask, int* __restrict__ dmask) {
  int b = blockIdx.x, t = threadIdx.x;  // 128 threads
  const float* A = adj + (size_t)b * SS * SS;
  float indeg = 0.f;
  for (int s = 0; s < SS; ++s) indeg += A[s * SS + t];
  float outdeg = 0.f;
  const float4* row = (const float4*)(A + t * SS);
#pragma unroll
  for (int i = 0; i < SS / 4; ++i) { float4 v = row[i]; outdeg += v.x + v.y + v.z + v.w; }
  int idx = b * SS + t;
  denom[idx] = outdeg + 1.f;
  pmask[idx] = ((indeg + outdeg) == 0.f) ? 1 : 0;
  dmask[idx] = (indeg == 0.f) ? 1 : 0;
}

// ---------------- embedding gather -> h0 [B*S, 360] ----------------
__global__ void k_embed(const int* __restrict__ words, const int* __restrict__ pos,
                        const int* __restrict__ ner,
                        const float* __restrict__ emb_w, const float* __restrict__ pos_w,
                        const float* __restrict__ ner_w, float* __restrict__ h) {
  int tid = threadIdx.x;  // 192 threads, 180 active (360 floats = 180 float2)
  int tok0 = blockIdx.x * 16;
  if (tid >= 180) return;
  int c = tid * 2;
  for (int i = 0; i < 16; ++i) {
    int tok = tok0 + i;
    float2 v;
    if (c < 300)      v = *(const float2*)(emb_w + (size_t)words[tok] * 300 + c);
    else if (c < 330) v = *(const float2*)(pos_w + (size_t)pos[tok] * 30 + (c - 300));
    else              v = *(const float2*)(ner_w + (size_t)ner[tok] * 30 + (c - 330));
    *(float2*)(h + (size_t)tok * DIN + c) = v;
  }
}

// ---------------- query = pool_max(h) ; qa = attn_w @ query ----------------
__global__ void k_query_qa(const float* __restrict__ h, const int* __restrict__ pmask,
                           const float* __restrict__ attn_w, float* __restrict__ qa) {
  __shared__ float q[DIN];
  __shared__ int pm[SS];
  int b = blockIdx.x, tid = threadIdx.x;  // 384 threads
  if (tid < SS) pm[tid] = pmask[b * SS + tid];
  __syncthreads();
  if (tid < DIN) {
    float m = -INF_;
    const float* hb = h + (size_t)b * SS * DIN + tid;
    for (int s = 0; s < SS; ++s) { float v = hb[(size_t)s * DIN]; if (!pm[s]) m = fmaxf(m, v); }
    q[tid] = m;
  }
  __syncthreads();
  if (tid < DDEPW) {
    const float* wr = attn_w + (size_t)tid * DIN;
    float acc = 0.f;
    for (int e = 0; e < DIN; ++e) acc += wr[e] * q[e];
    qa[b * SS + tid] = acc;
  }
}

// ---------------- scores -> softmax -> weights ----------------
__global__ void k_weights(const int* __restrict__ deprel, const float* __restrict__ dep_w,
                          const int* __restrict__ dmask, const float* __restrict__ qa,
                          float* __restrict__ wts) {
  __shared__ float qs[DDEPW];
  __shared__ float red[SS];
  int b = blockIdx.x, s = threadIdx.x;  // 128 threads
  if (s < DDEPW) qs[s] = qa[b * SS + s];
  __syncthreads();
  float score;
  if (dmask[b * SS + s]) score = NEG_;
  else {
    const float* dr = dep_w + (size_t)deprel[b * SS + s] * DDEPW;
    float acc = 0.f;
    for (int d = 0; d < DDEPW; ++d) acc += dr[d] * qs[d];
    score = acc;
  }
  red[s] = score; __syncthreads();
  for (int off = 64; off > 0; off >>= 1) { if (s < off) red[s] = fmaxf(red[s], red[s + off]); __syncthreads(); }
  float mx = red[0]; __syncthreads();
  float ex = expf(score - mx);  // expf(-1e30 - mx) underflows to 0, matching masked softmax
  red[s] = ex; __syncthreads();
  for (int off = 64; off > 0; off >>= 1) { if (s < off) red[s] += red[s + off]; __syncthreads(); }
  wts[b * SS + s] = ex / red[0];
}

// ---------------- a[s,t] = adj[s,t]*w[s] + adj[t,s]*w[t]  (symmetric) ----------------
// Skewed LDS layout: element (s,t) stored at [s*128 + ((t+s)&127)] -> both the
// row read and the transposed read are bank-conflict-free.
__global__ void k_symmetrize(const float* __restrict__ adj, const float* __restrict__ wts,
                             float* __restrict__ amat) {
  __shared__ float tile[SS * SS];  // 64 KiB exactly
  int b = blockIdx.x, tid = threadIdx.x;  // 256 threads
  const float* Ab = adj + (size_t)b * SS * SS;
  float* ab = amat + (size_t)b * SS * SS;
#pragma unroll 4
  for (int i = 0; i < 64; ++i) {
    int idx = i * 256 + tid;
    int s_ = idx >> 7, t_ = idx & 127;
    tile[(s_ << 7) + ((t_ + s_) & 127)] = Ab[idx];
  }
  __syncthreads();
  const float* wb = wts + b * SS;
#pragma unroll 4
  for (int i = 0; i < 64; ++i) {
    int idx = i * 256 + tid;
    int s_ = idx >> 7, t_ = idx & 127;
    float v = tile[(s_ << 7) + ((t_ + s_) & 127)] * wb[s_]
            + tile[(t_ << 7) + ((s_ + t_) & 127)] * wb[t_];
    ab[idx] = v;
  }
}

// ---------------- generic tiled fp32 GEMM with fused epilogues ----------------
template<bool RELU, bool DEN, bool ADDM>
__global__ __launch_bounds__(256) void k_gemm(
    const float* __restrict__ A, const float* __restrict__ Bm,
    const float* __restrict__ bias, float bscale,
    const float* __restrict__ denom, const float* __restrict__ Add,
    float* __restrict__ C, int M, int N, int K,
    long long sA, long long sB, long long sC) {
  __shared__ float As[16][68];  // [BK][BM+pad], row stride 272B (16B-aligned)
  __shared__ float Bs[16][68];
  int z = blockIdx.z;
  const float* Ab = A + (long long)z * sA;
  const float* Bb = Bm + (long long)z * sB;
  float* Cb = C + (long long)z * sC;
  const float* Addb = ADDM ? (Add + (long long)z * sC) : nullptr;
  int tid = threadIdx.x;
  int tx = tid & 15, ty = tid >> 4;
  int mblk = blockIdx.y * 64, nblk = blockIdx.x * 64;
  int m0 = ty * 4, n0 = tx * 4;
  float acc[4][4] = {};
  for (int k0 = 0; k0 < K; k0 += 16) {
#pragma unroll
    for (int i = 0; i < 4; ++i) {           // A tile 64x16
      int idx = i * 256 + tid;
      int r = idx >> 4, kk = idx & 15;
      int gk = k0 + kk;
      As[kk][r] = (gk < K) ? Ab[(size_t)(mblk + r) * K + gk] : 0.f;
    }
#pragma unroll
    for (int i = 0; i < 4; ++i) {           // B tile 16x64
      int idx = i * 256 + tid;
      int kk = idx >> 6, cc = idx & 63;
      int gk = k0 + kk, gn = nblk + cc;
      Bs[kk][cc] = (gk < K && gn < N) ? Bb[(size_t)gk * N + gn] : 0.f;
    }
    __syncthreads();
#pragma unroll
    for (int kk = 0; kk < 16; ++kk) {
      float4 av = *(const float4*)&As[kk][m0];
      float4 bv = *(const float4*)&Bs[kk][n0];
      float a4[4] = {av.x, av.y, av.z, av.w};
      float b4[4] = {bv.x, bv.y, bv.z, bv.w};
#pragma unroll
      for (int i2 = 0; i2 < 4; ++i2)
#pragma unroll
        for (int j = 0; j < 4; ++j) acc[i2][j] += a4[i2] * b4[j];
    }
    __syncthreads();
  }
#pragma unroll
  for (int i = 0; i < 4; ++i) {
    int m = mblk + m0 + i;
#pragma unroll
    for (int j = 0; j < 4; ++j) {
      int n = nblk + n0 + j;
      if (n < N) {
        float v = acc[i][j];
        if (bias) v += bscale * bias[n];
        if (ADDM) v += Addb[(size_t)m * N + n];
        if (DEN) v /= denom[m];
        if (RELU) v = fmaxf(v, 0.f);
        Cb[(size_t)m * N + n] = v;
      }
    }
  }
}

// ---------------- final 3-way masked max pool ----------------
__global__ void k_pool(const float* __restrict__ h, const int* __restrict__ pmask,
                       const int* __restrict__ subj_pos, const int* __restrict__ obj_pos,
                       float* __restrict__ cat, float* __restrict__ hout) {
  __shared__ int pm[SS], sm[SS], om[SS];
  int b = blockIdx.x, e = threadIdx.x;  // 320 threads
  if (e < SS) {
    pm[e] = pmask[b * SS + e];
    sm[e] = (subj_pos[b * SS + e] != 0) ? 1 : 0;
    om[e] = (obj_pos[b * SS + e] != 0) ? 1 : 0;
  }
  __syncthreads();
  if (e < DHID) {
    const float* hb = h + (size_t)b * SS * DHID + e;
    float mh = -INF_, ms = -INF_, mo = -INF_;
    for (int s = 0; s < SS; ++s) {
      float v = hb[(size_t)s * DHID];
      if (!pm[s]) mh = fmaxf(mh, v);
      if (!sm[s]) ms = fmaxf(ms, v);
      if (!om[s]) mo = fmaxf(mo, v);
    }
    cat[(size_t)b * 900 + e] = mh;
    cat[(size_t)b * 900 + 300 + e] = ms;
    cat[(size_t)b * 900 + 600 + e] = mo;
    hout[(size_t)b * DHID + e] = mh;  // second output (h_out)
  }
}

extern "C" void kernel_launch(void* const* d_in, const int* in_sizes, int n_in,
                              void* d_out, int out_size, void* d_ws, size_t ws_size,
                              hipStream_t stream) {
  const int* words = (const int*)d_in[0];
  const int* pos = (const int*)d_in[1];
  const int* ner = (const int*)d_in[2];
  const int* deprel = (const int*)d_in[3];
  const int* subj_pos = (const int*)d_in[4];
  const int* obj_pos = (const int*)d_in[5];
  const float* adj = (const float*)d_in[6];
  const float* emb_w = (const float*)d_in[7];
  const float* pos_w = (const float*)d_in[8];
  const float* ner_w = (const float*)d_in[9];
  const float* dep_w = (const float*)d_in[10];
  const float* attn_w = (const float*)d_in[11];
  const float* W0 = (const float*)d_in[12];
  const float* b0 = (const float*)d_in[13];
  const float* W1 = (const float*)d_in[14];
  const float* b1 = (const float*)d_in[15];
  const float* mlp0_w = (const float*)d_in[16];
  const float* mlp0_b = (const float*)d_in[17];
  const float* mlp1_w = (const float*)d_in[18];
  const float* mlp1_b = (const float*)d_in[19];
  const float* cls_w = (const float*)d_in[20];
  const float* cls_b = (const float*)d_in[21];
  float* out = (float*)d_out;

  // workspace layout (floats); liveness-based reuse, total ~216 MB:
  //   bufA: h0 [65536*360] -> h1 [65536*300] -> h2 [65536*300]
  //   bufB: t1 [65536*360] -> t2 [65536*300]
  // (h0 dead after t1; t1 dead after h1; h1 dead after t2; t2 dead after h2)
  float* ws = (float*)d_ws;
  float* bufA = ws;                        // 23,592,960 floats
  float* bufB = bufA + (size_t)23592960;   // 23,592,960 floats
  float* amat = bufB + (size_t)23592960;   // 8,388,608 floats
  float* denom = amat + (size_t)8388608;   // [65536]
  int* pmask = (int*)(denom + 65536);      // [65536]
  int* dmask = pmask + 65536;              // [65536]
  float* qa = (float*)(dmask + 65536);     // [512*128] (100 used/row)
  float* wts = qa + 65536;                 // [65536]
  float* cat = wts + 65536;                // [512*900]
  float* m0b = cat + 460800;               // [512*300]
  float* m1b = m0b + 153600;               // [512*300]

  float* h0 = bufA;
  k_degrees<<<NB, SS, 0, stream>>>(adj, denom, pmask, dmask);
  k_embed<<<(NB * SS) / 16, 192, 0, stream>>>(words, pos, ner, emb_w, pos_w, ner_w, h0);
  k_query_qa<<<NB, 384, 0, stream>>>(h0, pmask, attn_w, qa);
  k_weights<<<NB, SS, 0, stream>>>(deprel, dep_w, dmask, qa, wts);
  k_symmetrize<<<NB, 256, 0, stream>>>(adj, wts, amat);

  // Layer 1: t1 = a@h0 + h0   (batched: M=128,N=360,K=128) -> bufB
  float* t1 = bufB;
  dim3 g1((DIN + 63) / 64, SS / 64, NB);
  k_gemm<false, false, true><<<g1, 256, 0, stream>>>(
      amat, h0, nullptr, 0.f, nullptr, h0, t1, SS, DIN, SS,
      (long long)SS * SS, (long long)SS * DIN, (long long)SS * DIN);
  // h1 = relu((t1@W0 + 2*b0)/denom)   (M=65536,N=300,K=360) -> bufA (h0 dead)
  float* h1 = bufA;
  dim3 g2((DHID + 63) / 64, (NB * SS) / 64, 1);
  k_gemm<true, true, false><<<g2, 256, 0, stream>>>(
      t1, W0, b0, 2.f, denom, nullptr, h1, NB * SS, DHID, DIN, 0, 0, 0);

  // Layer 2: t2 = a@h1 + h1   (M=128,N=300,K=128) -> bufB (t1 dead)
  float* t2 = bufB;
  dim3 g3((DHID + 63) / 64, SS / 64, NB);
  k_gemm<false, false, true><<<g3, 256, 0, stream>>>(
      amat, h1, nullptr, 0.f, nullptr, h1, t2, SS, DHID, SS,
      (long long)SS * SS, (long long)SS * DHID, (long long)SS * DHID);
  // h2 = relu((t2@W1 + 2*b1)/denom) -> bufA (h1 dead)
  float* h2 = bufA;
  k_gemm<true, true, false><<<g2, 256, 0, stream>>>(
      t2, W1, b1, 2.f, denom, nullptr, h2, NB * SS, DHID, DHID, 0, 0, 0);

  // pools -> cat [512,900]; h_out -> out+21504
  k_pool<<<NB, 320, 0, stream>>>(h2, pmask, subj_pos, obj_pos, cat, out + NB * NCLS);

  // MLP + classifier
  dim3 g4((DHID + 63) / 64, NB / 64, 1);
  k_gemm<true, false, false><<<g4, 256, 0, stream>>>(
      cat, mlp0_w, mlp0_b, 1.f, nullptr, nullptr, m0b, NB, DHID, 900, 0, 0, 0);
  k_gemm<true, false, false><<<g4, 256, 0, stream>>>(
      m0b, mlp1_w, mlp1_b, 1.f, nullptr, nullptr, m1b, NB, DHID, DHID, 0, 0, 0);
  dim3 g5(1, NB / 64, 1);
  k_gemm<false, false, false><<<g5, 256, 0, stream>>>(
      m1b, cls_w, cls_b, 1.f, nullptr, nullptr, out, NB, NCLS, DHID, 0, 0, 0);
}

// Round 5
// 754.813 us; speedup vs baseline: 1.8031x; 1.8031x over previous
//
#include <hip/hip_runtime.h>
#include <cstdint>

typedef __bf16 bf16;
typedef bf16 bf16x8 __attribute__((ext_vector_type(8)));
typedef float f32x4 __attribute__((ext_vector_type(4)));

#define NB 512     // batch
#define SS 128     // sequence
#define DIN 360    // emb(300)+pos(30)+ner(30)
#define DINP 384   // DIN padded to mult of 32 (zero pad)
#define DHID 300
#define DHP 320    // DHID padded to mult of 32
#define DDEPW 100
#define NCLS 42

constexpr float INF_ = 1e12f;
constexpr float NEG_ = -1e30f;

// ---------------- degrees / masks / denom (fp32, unchanged) ----------------
__global__ void k_degrees(const float* __restrict__ adj, float* __restrict__ denom,
                          int* __restrict__ pmask, int* __restrict__ dmask) {
  int b = blockIdx.x, t = threadIdx.x;  // 128 threads
  const float* A = adj + (size_t)b * SS * SS;
  float indeg = 0.f;
  for (int s = 0; s < SS; ++s) indeg += A[s * SS + t];
  float outdeg = 0.f;
  const float4* row = (const float4*)(A + t * SS);
#pragma unroll
  for (int i = 0; i < SS / 4; ++i) { float4 v = row[i]; outdeg += v.x + v.y + v.z + v.w; }
  int idx = b * SS + t;
  denom[idx] = outdeg + 1.f;
  pmask[idx] = ((indeg + outdeg) == 0.f) ? 1 : 0;
  dmask[idx] = (indeg == 0.f) ? 1 : 0;
}

// ---------------- embedding gather -> h0 bf16 [B*S][384], cols 360..383 zero ----
__global__ void k_embed(const int* __restrict__ words, const int* __restrict__ pos,
                        const int* __restrict__ ner,
                        const float* __restrict__ emb_w, const float* __restrict__ pos_w,
                        const float* __restrict__ ner_w, bf16* __restrict__ h) {
  int tid = threadIdx.x;  // 192 threads: 180 data (2 floats each), 12 pad-zero
  int tok0 = blockIdx.x * 16;
  for (int i = 0; i < 16; ++i) {
    int tok = tok0 + i;
    if (tid < 180) {
      int c = tid * 2;
      float2 v;
      if (c < 300)      v = *(const float2*)(emb_w + (size_t)words[tok] * 300 + c);
      else if (c < 330) v = *(const float2*)(pos_w + (size_t)pos[tok] * 30 + (c - 300));
      else              v = *(const float2*)(ner_w + (size_t)ner[tok] * 30 + (c - 330));
      union { bf16 b[2]; uint32_t u; } cvt;
      cvt.b[0] = (bf16)v.x; cvt.b[1] = (bf16)v.y;
      *(uint32_t*)(h + (size_t)tok * DINP + c) = cvt.u;
    } else {
      int c = 360 + (tid - 180) * 2;
      *(uint32_t*)(h + (size_t)tok * DINP + c) = 0u;
    }
  }
}

// ---------------- W [K][N] fp32 -> WT bf16 [RP][SP] zero-padded ----------------
__global__ void k_prepw(const float* __restrict__ W, int K, int N,
                        bf16* __restrict__ WT, int RP, int SP) {
  int idx = blockIdx.x * 256 + threadIdx.x;
  if (idx >= RP * SP) return;
  int r = idx / SP, c = idx % SP;
  float v = (r < N && c < K) ? W[(size_t)c * N + r] : 0.f;
  WT[(size_t)r * SP + c] = (bf16)v;
}

// ---------------- query = pool_max(h0) ; qa = attn_w @ query ----------------
__global__ void k_query_qa(const bf16* __restrict__ h, const int* __restrict__ pmask,
                           const float* __restrict__ attn_w, float* __restrict__ qa) {
  __shared__ float q[DIN];
  __shared__ int pm[SS];
  int b = blockIdx.x, tid = threadIdx.x;  // 384 threads
  if (tid < SS) pm[tid] = pmask[b * SS + tid];
  __syncthreads();
  if (tid < DIN) {
    float m = -INF_;
    const bf16* hb = h + (size_t)b * SS * DINP + tid;
    for (int s = 0; s < SS; ++s) { float v = (float)hb[(size_t)s * DINP]; if (!pm[s]) m = fmaxf(m, v); }
    q[tid] = m;
  }
  __syncthreads();
  if (tid < DDEPW) {
    const float* wr = attn_w + (size_t)tid * DIN;
    float acc = 0.f;
    for (int e = 0; e < DIN; ++e) acc += wr[e] * q[e];
    qa[b * SS + tid] = acc;
  }
}

// ---------------- scores -> softmax -> weights (fp32, unchanged) ----------------
__global__ void k_weights(const int* __restrict__ deprel, const float* __restrict__ dep_w,
                          const int* __restrict__ dmask, const float* __restrict__ qa,
                          float* __restrict__ wts) {
  __shared__ float qs[DDEPW];
  __shared__ float red[SS];
  int b = blockIdx.x, s = threadIdx.x;  // 128 threads
  if (s < DDEPW) qs[s] = qa[b * SS + s];
  __syncthreads();
  float score;
  if (dmask[b * SS + s]) score = NEG_;
  else {
    const float* dr = dep_w + (size_t)deprel[b * SS + s] * DDEPW;
    float acc = 0.f;
    for (int d = 0; d < DDEPW; ++d) acc += dr[d] * qs[d];
    score = acc;
  }
  red[s] = score; __syncthreads();
  for (int off = 64; off > 0; off >>= 1) { if (s < off) red[s] = fmaxf(red[s], red[s + off]); __syncthreads(); }
  float mx = red[0]; __syncthreads();
  float ex = expf(score - mx);
  red[s] = ex; __syncthreads();
  for (int off = 64; off > 0; off >>= 1) { if (s < off) red[s] += red[s + off]; __syncthreads(); }
  wts[b * SS + s] = ex / red[0];
}

// ---------------- amat bf16: a[s,t] = adj[s,t]*w[s] + adj[t,s]*w[t] ----------------
__global__ void k_symmetrize(const float* __restrict__ adj, const float* __restrict__ wts,
                             bf16* __restrict__ amat) {
  __shared__ float tile[SS * SS];  // 64 KiB, skewed: (s,t) at [s*128 + ((t+s)&127)]
  int b = blockIdx.x, tid = threadIdx.x;  // 256 threads
  const float* Ab = adj + (size_t)b * SS * SS;
  bf16* ab = amat + (size_t)b * SS * SS;
#pragma unroll 4
  for (int i = 0; i < 64; ++i) {
    int idx = i * 256 + tid;
    int s_ = idx >> 7, t_ = idx & 127;
    tile[(s_ << 7) + ((t_ + s_) & 127)] = Ab[idx];
  }
  __syncthreads();
  const float* wb = wts + b * SS;
#pragma unroll 4
  for (int i = 0; i < 64; ++i) {
    int idx = i * 256 + tid;
    int s_ = idx >> 7, t_ = idx & 127;
    float v = tile[(s_ << 7) + ((t_ + s_) & 127)] * wb[s_]
            + tile[(t_ << 7) + ((s_ + t_) & 127)] * wb[t_];
    ab[idx] = (bf16)v;
  }
}

// ---------------- batched MFMA: t[z] = amat[z] @ h[z] + h[z] ----------------
// X=amat [128][128] bf16 K-contig; h [128][SH] bf16 row-major (B-frags via u16 reads).
// out t bf16 [z*128+m][ST]; n<NVALID: acc+h, NVALID<=n<ST: 0.
__global__ __launch_bounds__(256) void k_ah(
    const bf16* __restrict__ amat, const bf16* __restrict__ h,
    int SH, int NVALID, bf16* __restrict__ t, int ST) {
  __shared__ __align__(16) bf16 Xs[128 * 136];
  __shared__ __align__(16) bf16 Ys[32 * 136];
  int z = blockIdx.y;
  int nblk = blockIdx.x * 128;
  int tid = threadIdx.x;
  const bf16* Az = amat + (size_t)z * SS * SS;
  const bf16* hz = h + (size_t)z * SS * SH;
  {  // stage whole 128x128 amat tile (b128, coalesced)
    int c8 = (tid & 15) * 8;
#pragma unroll
    for (int it = 0; it < 8; ++it) {
      int r = it * 16 + (tid >> 4);
      *(bf16x8*)&Xs[r * 136 + c8] = *(const bf16x8*)&Az[r * SS + c8];
    }
  }
  int wid = tid >> 6, lane = tid & 63;
  int wm = (wid >> 1) * 64, wn = (wid & 1) * 64;
  int lr = lane & 15, lg = lane >> 4;
  f32x4 acc[4][4];
#pragma unroll
  for (int i = 0; i < 4; ++i)
#pragma unroll
    for (int j = 0; j < 4; ++j) acc[i][j] = (f32x4){0.f, 0.f, 0.f, 0.f};

  for (int k0 = 0; k0 < SS; k0 += 32) {
    {  // stage Ys = h rows k0..k0+31, cols nblk..nblk+127 (row-major, b128)
      int c8 = (tid & 15) * 8;
      int col = nblk + c8;
#pragma unroll
      for (int it = 0; it < 2; ++it) {
        int r = it * 16 + (tid >> 4);
        bf16x8 v;
        if (col < SH) v = *(const bf16x8*)&hz[(size_t)(k0 + r) * SH + col];
        else { union { uint32_t u[4]; bf16x8 bv; } zz; zz.u[0]=zz.u[1]=zz.u[2]=zz.u[3]=0u; v = zz.bv; }
        *(bf16x8*)&Ys[r * 136 + c8] = v;
      }
    }
    __syncthreads();
    bf16x8 a[4], b[4];
#pragma unroll
    for (int mi = 0; mi < 4; ++mi)
      a[mi] = *(const bf16x8*)&Xs[(wm + mi * 16 + lr) * 136 + k0 + lg * 8];
#pragma unroll
    for (int nf = 0; nf < 4; ++nf) {
      bf16x8 bv;
#pragma unroll
      for (int i = 0; i < 8; ++i) bv[i] = Ys[(lg * 8 + i) * 136 + wn + nf * 16 + lr];
      b[nf] = bv;
    }
#pragma unroll
    for (int mi = 0; mi < 4; ++mi)
#pragma unroll
      for (int nf = 0; nf < 4; ++nf)
        acc[mi][nf] = __builtin_amdgcn_mfma_f32_16x16x32_bf16(a[mi], b[nf], acc[mi][nf], 0, 0, 0);
    __syncthreads();
  }
  // epilogue: t = acc + h (h pads are zero for a@h0; explicit 0 for NVALID<=n<ST)
#pragma unroll
  for (int mi = 0; mi < 4; ++mi) {
    int m = wm + mi * 16 + lg * 4;
#pragma unroll
    for (int nf = 0; nf < 4; ++nf) {
      int n = nblk + wn + nf * 16 + lr;
      if (n < ST) {
#pragma unroll
        for (int i = 0; i < 4; ++i) {
          float v = (n < NVALID) ? (acc[mi][nf][i] + (float)hz[(size_t)(m + i) * SH + n]) : 0.f;
          t[((size_t)z * SS + m + i) * ST + n] = (bf16)v;
        }
      }
    }
  }
}

// ---------------- dense MFMA: C = relu((X @ Y^T + 2*bias)/denom) ----------------
// X [65536][K] bf16, Y [.][K] bf16 (pre-transposed W, zero-padded). BM=128 BN=160.
template<bool F32OUT>
__global__ __launch_bounds__(256) void k_dense(
    const bf16* __restrict__ X, const bf16* __restrict__ Y,
    const float* __restrict__ bias, const float* __restrict__ denom,
    void* __restrict__ Cout, int K, int NVALID, int SC) {
  __shared__ __align__(16) bf16 As[128 * 40];
  __shared__ __align__(16) bf16 Bs[160 * 40];
  int tid = threadIdx.x;
  int mblk = blockIdx.y * 128, nblk = blockIdx.x * 160;
  int wid = tid >> 6, lane = tid & 63;
  int wm = (wid >> 1) * 64, wn = (wid & 1) * 80;
  int lr = lane & 15, lg = lane >> 4;
  f32x4 acc[4][5];
#pragma unroll
  for (int i = 0; i < 4; ++i)
#pragma unroll
    for (int j = 0; j < 5; ++j) acc[i][j] = (f32x4){0.f, 0.f, 0.f, 0.f};
  int rA = tid >> 2, kA = (tid & 3) * 8;
  for (int k0 = 0; k0 < K; k0 += 32) {
#pragma unroll
    for (int it = 0; it < 2; ++it) {
      int r = it * 64 + rA;
      *(bf16x8*)&As[r * 40 + kA] = *(const bf16x8*)&X[(size_t)(mblk + r) * K + k0 + kA];
    }
#pragma unroll
    for (int it = 0; it < 3; ++it) {
      int r = it * 64 + rA;
      if (r < 160)
        *(bf16x8*)&Bs[r * 40 + kA] = *(const bf16x8*)&Y[(size_t)(nblk + r) * K + k0 + kA];
    }
    __syncthreads();
    bf16x8 a[4], b[5];
#pragma unroll
    for (int mi = 0; mi < 4; ++mi)
      a[mi] = *(const bf16x8*)&As[(wm + mi * 16 + lr) * 40 + lg * 8];
#pragma unroll
    for (int nf = 0; nf < 5; ++nf)
      b[nf] = *(const bf16x8*)&Bs[(wn + nf * 16 + lr) * 40 + lg * 8];
#pragma unroll
    for (int mi = 0; mi < 4; ++mi)
#pragma unroll
      for (int nf = 0; nf < 5; ++nf)
        acc[mi][nf] = __builtin_amdgcn_mfma_f32_16x16x32_bf16(a[mi], b[nf], acc[mi][nf], 0, 0, 0);
    __syncthreads();
  }
#pragma unroll
  for (int mi = 0; mi < 4; ++mi) {
    int m0 = mblk + wm + mi * 16 + lg * 4;
    float dn[4];
#pragma unroll
    for (int i = 0; i < 4; ++i) dn[i] = denom[m0 + i];
#pragma unroll
    for (int nf = 0; nf < 5; ++nf) {
      int n = nblk + wn + nf * 16 + lr;
      if (n < NVALID) {
        float bs = 2.f * bias[n];
#pragma unroll
        for (int i = 0; i < 4; ++i) {
          float v = fmaxf((acc[mi][nf][i] + bs) / dn[i], 0.f);
          if (F32OUT) ((float*)Cout)[(size_t)(m0 + i) * SC + n] = v;
          else ((bf16*)Cout)[(size_t)(m0 + i) * SC + n] = (bf16)v;
        }
      }
    }
  }
}

// ---------------- fp32 tiled GEMM for the small MLP/classifier ----------------
template<bool RELU>
__global__ __launch_bounds__(256) void k_gemm(
    const float* __restrict__ A, const float* __restrict__ Bm,
    const float* __restrict__ bias, float* __restrict__ C, int M, int N, int K) {
  __shared__ float As[16][68];
  __shared__ float Bs[16][68];
  int tid = threadIdx.x;
  int tx = tid & 15, ty = tid >> 4;
  int mblk = blockIdx.y * 64, nblk = blockIdx.x * 64;
  int m0 = ty * 4, n0 = tx * 4;
  float acc[4][4] = {};
  for (int k0 = 0; k0 < K; k0 += 16) {
#pragma unroll
    for (int i = 0; i < 4; ++i) {
      int idx = i * 256 + tid;
      int r = idx >> 4, kk = idx & 15;
      int gk = k0 + kk;
      As[kk][r] = (gk < K) ? A[(size_t)(mblk + r) * K + gk] : 0.f;
    }
#pragma unroll
    for (int i = 0; i < 4; ++i) {
      int idx = i * 256 + tid;
      int kk = idx >> 6, cc = idx & 63;
      int gk = k0 + kk, gn = nblk + cc;
      Bs[kk][cc] = (gk < K && gn < N) ? Bm[(size_t)gk * N + gn] : 0.f;
    }
    __syncthreads();
#pragma unroll
    for (int kk = 0; kk < 16; ++kk) {
      float4 av = *(const float4*)&As[kk][m0];
      float4 bv = *(const float4*)&Bs[kk][n0];
      float a4[4] = {av.x, av.y, av.z, av.w};
      float b4[4] = {bv.x, bv.y, bv.z, bv.w};
#pragma unroll
      for (int i2 = 0; i2 < 4; ++i2)
#pragma unroll
        for (int j = 0; j < 4; ++j) acc[i2][j] += a4[i2] * b4[j];
    }
    __syncthreads();
  }
#pragma unroll
  for (int i = 0; i < 4; ++i) {
    int m = mblk + m0 + i;
#pragma unroll
    for (int j = 0; j < 4; ++j) {
      int n = nblk + n0 + j;
      if (n < N) {
        float v = acc[i][j] + bias[n];
        if (RELU) v = fmaxf(v, 0.f);
        C[(size_t)m * N + n] = v;
      }
    }
  }
}

// ---------------- final 3-way masked max pool (h2 fp32) ----------------
__global__ void k_pool(const float* __restrict__ h, const int* __restrict__ pmask,
                       const int* __restrict__ subj_pos, const int* __restrict__ obj_pos,
                       float* __restrict__ cat, float* __restrict__ hout) {
  __shared__ int pm[SS], sm[SS], om[SS];
  int b = blockIdx.x, e = threadIdx.x;  // 320 threads
  if (e < SS) {
    pm[e] = pmask[b * SS + e];
    sm[e] = (subj_pos[b * SS + e] != 0) ? 1 : 0;
    om[e] = (obj_pos[b * SS + e] != 0) ? 1 : 0;
  }
  __syncthreads();
  if (e < DHID) {
    const float* hb = h + (size_t)b * SS * DHID + e;
    float mh = -INF_, ms = -INF_, mo = -INF_;
    for (int s = 0; s < SS; ++s) {
      float v = hb[(size_t)s * DHID];
      if (!pm[s]) mh = fmaxf(mh, v);
      if (!sm[s]) ms = fmaxf(ms, v);
      if (!om[s]) mo = fmaxf(mo, v);
    }
    cat[(size_t)b * 900 + e] = mh;
    cat[(size_t)b * 900 + 300 + e] = ms;
    cat[(size_t)b * 900 + 600 + e] = mo;
    hout[(size_t)b * DHID + e] = mh;
  }
}

extern "C" void kernel_launch(void* const* d_in, const int* in_sizes, int n_in,
                              void* d_out, int out_size, void* d_ws, size_t ws_size,
                              hipStream_t stream) {
  const int* words = (const int*)d_in[0];
  const int* pos = (const int*)d_in[1];
  const int* ner = (const int*)d_in[2];
  const int* deprel = (const int*)d_in[3];
  const int* subj_pos = (const int*)d_in[4];
  const int* obj_pos = (const int*)d_in[5];
  const float* adj = (const float*)d_in[6];
  const float* emb_w = (const float*)d_in[7];
  const float* pos_w = (const float*)d_in[8];
  const float* ner_w = (const float*)d_in[9];
  const float* dep_w = (const float*)d_in[10];
  const float* attn_w = (const float*)d_in[11];
  const float* W0 = (const float*)d_in[12];
  const float* b0 = (const float*)d_in[13];
  const float* W1 = (const float*)d_in[14];
  const float* b1 = (const float*)d_in[15];
  const float* mlp0_w = (const float*)d_in[16];
  const float* mlp0_b = (const float*)d_in[17];
  const float* mlp1_w = (const float*)d_in[18];
  const float* mlp1_b = (const float*)d_in[19];
  const float* cls_w = (const float*)d_in[20];
  const float* cls_b = (const float*)d_in[21];
  float* out = (float*)d_out;

  // -------- workspace carve (~151 MB), liveness reuse --------
  char* w = (char*)d_ws;
  bf16* h0 = (bf16*)w;        // [65536][384] bf16 -> later h1 [65536][320] bf16 -> h2f [65536][300] f32
  bf16* h1 = (bf16*)w;
  float* h2f = (float*)w;
  w += 78643200;
  bf16* t1 = (bf16*)w;        // [65536][384] bf16 -> later t2 [65536][320]
  bf16* t2 = (bf16*)w;
  w += 50331648;
  bf16* amat = (bf16*)w; w += 16777216;   // [512][128][128]
  bf16* W0T = (bf16*)w; w += 294912;      // [384][384]
  bf16* W1T = (bf16*)w; w += 204800;      // [320][320]
  float* denom = (float*)w; w += 262144;
  int* pmask = (int*)w; w += 262144;
  int* dmask = (int*)w; w += 262144;
  float* qa = (float*)w; w += 262144;
  float* wts = (float*)w; w += 262144;
  float* cat = (float*)w; w += 1843200;
  float* m0b = (float*)w; w += 614400;
  float* m1b = (float*)w; w += 614400;

  k_prepw<<<(384 * 384 + 255) / 256, 256, 0, stream>>>(W0, DIN, DHID, W0T, DINP, DINP);
  k_prepw<<<(320 * 320 + 255) / 256, 256, 0, stream>>>(W1, DHID, DHID, W1T, DHP, DHP);
  k_degrees<<<NB, SS, 0, stream>>>(adj, denom, pmask, dmask);
  k_embed<<<(NB * SS) / 16, 192, 0, stream>>>(words, pos, ner, emb_w, pos_w, ner_w, h0);
  k_query_qa<<<NB, 384, 0, stream>>>(h0, pmask, attn_w, qa);
  k_weights<<<NB, SS, 0, stream>>>(deprel, dep_w, dmask, qa, wts);
  k_symmetrize<<<NB, 256, 0, stream>>>(adj, wts, amat);

  // Layer 1: t1 = a@h0 + h0   (bf16 MFMA, batched)
  k_ah<<<dim3(3, NB), 256, 0, stream>>>(amat, h0, DINP, DINP, t1, DINP);
  // h1 = relu((t1@W0 + 2*b0)/denom)  -> bf16 [65536][320]
  k_dense<false><<<dim3(2, NB), 256, 0, stream>>>(t1, W0T, b0, denom, h1, DINP, DHID, DHP);
  // Layer 2: t2 = a@h1 + h1
  k_ah<<<dim3(3, NB), 256, 0, stream>>>(amat, h1, DHP, DHID, t2, DHP);
  // h2 = relu((t2@W1 + 2*b1)/denom)  -> fp32 [65536][300]
  k_dense<true><<<dim3(2, NB), 256, 0, stream>>>(t2, W1T, b1, denom, h2f, DHP, DHID, DHID);

  // pools -> cat [512,900]; h_out -> out + NB*NCLS
  k_pool<<<NB, 320, 0, stream>>>(h2f, pmask, subj_pos, obj_pos, cat, out + NB * NCLS);

  // MLP + classifier (fp32)
  dim3 g4((DHID + 63) / 64, NB / 64, 1);
  k_gemm<true><<<g4, 256, 0, stream>>>(cat, mlp0_w, mlp0_b, m0b, NB, DHID, 900);
  k_gemm<true><<<g4, 256, 0, stream>>>(m0b, mlp1_w, mlp1_b, m1b, NB, DHID, DHID);
  dim3 g5(1, NB / 64, 1);
  k_gemm<false><<<g5, 256, 0, stream>>>(m1b, cls_w, cls_b, out, NB, NCLS, DHID);
}

// Round 7
// 622.704 us; speedup vs baseline: 2.1857x; 1.2122x over previous
//
#include <hip/hip_runtime.h>
#include <cstdint>

typedef __bf16 bf16;
typedef bf16 bf16x8 __attribute__((ext_vector_type(8)));
typedef float f32x4 __attribute__((ext_vector_type(4)));

#define NB 512     // batch
#define SS 128     // sequence
#define DIN 360    // emb(300)+pos(30)+ner(30)
#define DINP 384   // DIN padded to mult of 32 (zero pad)
#define DHID 300
#define DHP 320    // DHID padded to mult of 32
#define DDEPW 100
#define NCLS 42

constexpr float INF_ = 1e12f;
constexpr float NEG_ = -1e30f;

// ---------------- degrees / masks / denom (fp32) ----------------
__global__ void k_degrees(const float* __restrict__ adj, float* __restrict__ denom,
                          int* __restrict__ pmask, int* __restrict__ dmask) {
  int b = blockIdx.x, t = threadIdx.x;  // 128 threads
  const float* A = adj + (size_t)b * SS * SS;
  float indeg = 0.f;
  for (int s = 0; s < SS; ++s) indeg += A[s * SS + t];
  float outdeg = 0.f;
  const float4* row = (const float4*)(A + t * SS);
#pragma unroll
  for (int i = 0; i < SS / 4; ++i) { float4 v = row[i]; outdeg += v.x + v.y + v.z + v.w; }
  int idx = b * SS + t;
  denom[idx] = outdeg + 1.f;
  pmask[idx] = ((indeg + outdeg) == 0.f) ? 1 : 0;
  dmask[idx] = (indeg == 0.f) ? 1 : 0;
}

// ---------------- embedding gather -> h0 bf16 [B*S][384], cols 360..383 zero ----
__global__ void k_embed(const int* __restrict__ words, const int* __restrict__ pos,
                        const int* __restrict__ ner,
                        const float* __restrict__ emb_w, const float* __restrict__ pos_w,
                        const float* __restrict__ ner_w, bf16* __restrict__ h) {
  int tid = threadIdx.x;  // 192 threads: 180 data (2 floats each), 12 pad-zero
  int tok0 = blockIdx.x * 16;
  for (int i = 0; i < 16; ++i) {
    int tok = tok0 + i;
    if (tid < 180) {
      int c = tid * 2;
      float2 v;
      if (c < 300)      v = *(const float2*)(emb_w + (size_t)words[tok] * 300 + c);
      else if (c < 330) v = *(const float2*)(pos_w + (size_t)pos[tok] * 30 + (c - 300));
      else              v = *(const float2*)(ner_w + (size_t)ner[tok] * 30 + (c - 330));
      union { bf16 b[2]; uint32_t u; } cvt;
      cvt.b[0] = (bf16)v.x; cvt.b[1] = (bf16)v.y;
      *(uint32_t*)(h + (size_t)tok * DINP + c) = cvt.u;
    } else {
      int c = 360 + (tid - 180) * 2;
      *(uint32_t*)(h + (size_t)tok * DINP + c) = 0u;
    }
  }
}

// ---------------- W [K][N] fp32 -> WT bf16 [RP][SP] zero-padded ----------------
__global__ void k_prepw(const float* __restrict__ W, int K, int N,
                        bf16* __restrict__ WT, int RP, int SP) {
  int idx = blockIdx.x * 256 + threadIdx.x;
  if (idx >= RP * SP) return;
  int r = idx / SP, c = idx % SP;
  float v = (r < N && c < K) ? W[(size_t)c * N + r] : 0.f;
  WT[(size_t)r * SP + c] = (bf16)v;
}

// ---------------- W [K][N] fp32 -> WT fp32 [N][K] (MLP weights) ----------------
__global__ void k_prepwf(const float* __restrict__ W, int K, int N,
                         float* __restrict__ WT) {
  int idx = blockIdx.x * 256 + threadIdx.x;
  if (idx >= N * K) return;
  int n = idx / K, k = idx % K;
  WT[(size_t)n * K + k] = W[(size_t)k * N + n];
}

// ---------------- query = pool_max(h0) ; qa = attn_w @ query ----------------
__global__ void k_query_qa(const bf16* __restrict__ h, const int* __restrict__ pmask,
                           const float* __restrict__ attn_w, float* __restrict__ qa) {
  __shared__ float q[DIN];
  __shared__ int pm[SS];
  int b = blockIdx.x, tid = threadIdx.x;  // 384 threads
  if (tid < SS) pm[tid] = pmask[b * SS + tid];
  __syncthreads();
  if (tid < DIN) {
    float m = -INF_;
    const bf16* hb = h + (size_t)b * SS * DINP + tid;
    for (int s = 0; s < SS; ++s) { float v = (float)hb[(size_t)s * DINP]; if (!pm[s]) m = fmaxf(m, v); }
    q[tid] = m;
  }
  __syncthreads();
  if (tid < DDEPW) {
    const float* wr = attn_w + (size_t)tid * DIN;
    float acc = 0.f;
    for (int e = 0; e < DIN; ++e) acc += wr[e] * q[e];
    qa[b * SS + tid] = acc;
  }
}

// ---------------- scores -> softmax -> weights (fp32) ----------------
__global__ void k_weights(const int* __restrict__ deprel, const float* __restrict__ dep_w,
                          const int* __restrict__ dmask, const float* __restrict__ qa,
                          float* __restrict__ wts) {
  __shared__ float qs[DDEPW];
  __shared__ float red[SS];
  int b = blockIdx.x, s = threadIdx.x;  // 128 threads
  if (s < DDEPW) qs[s] = qa[b * SS + s];
  __syncthreads();
  float score;
  if (dmask[b * SS + s]) score = NEG_;
  else {
    const float* dr = dep_w + (size_t)deprel[b * SS + s] * DDEPW;
    float acc = 0.f;
    for (int d = 0; d < DDEPW; ++d) acc += dr[d] * qs[d];
    score = acc;
  }
  red[s] = score; __syncthreads();
  for (int off = 64; off > 0; off >>= 1) { if (s < off) red[s] = fmaxf(red[s], red[s + off]); __syncthreads(); }
  float mx = red[0]; __syncthreads();
  float ex = expf(score - mx);
  red[s] = ex; __syncthreads();
  for (int off = 64; off > 0; off >>= 1) { if (s < off) red[s] += red[s + off]; __syncthreads(); }
  wts[b * SS + s] = ex / red[0];
}

// ---------------- amat bf16: a[s,t] = adj[s,t]*w[s] + adj[t,s]*w[t] ----------------
__global__ void k_symmetrize(const float* __restrict__ adj, const float* __restrict__ wts,
                             bf16* __restrict__ amat) {
  __shared__ float tile[SS * SS];  // 64 KiB, skewed: (s,t) at [s*128 + ((t+s)&127)]
  int b = blockIdx.x, tid = threadIdx.x;  // 256 threads
  const float* Ab = adj + (size_t)b * SS * SS;
  bf16* ab = amat + (size_t)b * SS * SS;
#pragma unroll 4
  for (int i = 0; i < 64; ++i) {
    int idx = i * 256 + tid;
    int s_ = idx >> 7, t_ = idx & 127;
    tile[(s_ << 7) + ((t_ + s_) & 127)] = Ab[idx];
  }
  __syncthreads();
  const float* wb = wts + b * SS;
#pragma unroll 4
  for (int i = 0; i < 64; ++i) {
    int idx = i * 256 + tid;
    int s_ = idx >> 7, t_ = idx & 127;
    float v = tile[(s_ << 7) + ((t_ + s_) & 127)] * wb[s_]
            + tile[(t_ << 7) + ((s_ + t_) & 127)] * wb[t_];
    ab[idx] = (bf16)v;
  }
}

// ---------------- batched MFMA: t[z] = amat[z] @ h[z] + h[z] ----------------
__global__ __launch_bounds__(256) void k_ah(
    const bf16* __restrict__ amat, const bf16* __restrict__ h,
    int SH, int NVALID, bf16* __restrict__ t, int ST) {
  __shared__ __align__(16) bf16 Xs[128 * 136];
  __shared__ __align__(16) bf16 Ys[32 * 136];
  int z = blockIdx.y;
  int nblk = blockIdx.x * 128;
  int tid = threadIdx.x;
  const bf16* Az = amat + (size_t)z * SS * SS;
  const bf16* hz = h + (size_t)z * SS * SH;
  {  // stage whole 128x128 amat tile (b128, coalesced)
    int c8 = (tid & 15) * 8;
#pragma unroll
    for (int it = 0; it < 8; ++it) {
      int r = it * 16 + (tid >> 4);
      *(bf16x8*)&Xs[r * 136 + c8] = *(const bf16x8*)&Az[r * SS + c8];
    }
  }
  int wid = tid >> 6, lane = tid & 63;
  int wm = (wid >> 1) * 64, wn = (wid & 1) * 64;
  int lr = lane & 15, lg = lane >> 4;
  f32x4 acc[4][4];
#pragma unroll
  for (int i = 0; i < 4; ++i)
#pragma unroll
    for (int j = 0; j < 4; ++j) acc[i][j] = (f32x4){0.f, 0.f, 0.f, 0.f};

  for (int k0 = 0; k0 < SS; k0 += 32) {
    {  // stage Ys = h rows k0..k0+31, cols nblk..nblk+127
      int c8 = (tid & 15) * 8;
      int col = nblk + c8;
#pragma unroll
      for (int it = 0; it < 2; ++it) {
        int r = it * 16 + (tid >> 4);
        bf16x8 v;
        if (col < SH) v = *(const bf16x8*)&hz[(size_t)(k0 + r) * SH + col];
        else { union { uint32_t u[4]; bf16x8 bv; } zz; zz.u[0]=zz.u[1]=zz.u[2]=zz.u[3]=0u; v = zz.bv; }
        *(bf16x8*)&Ys[r * 136 + c8] = v;
      }
    }
    __syncthreads();
    bf16x8 a[4], b[4];
#pragma unroll
    for (int mi = 0; mi < 4; ++mi)
      a[mi] = *(const bf16x8*)&Xs[(wm + mi * 16 + lr) * 136 + k0 + lg * 8];
#pragma unroll
    for (int nf = 0; nf < 4; ++nf) {
      bf16x8 bv;
#pragma unroll
      for (int i = 0; i < 8; ++i) bv[i] = Ys[(lg * 8 + i) * 136 + wn + nf * 16 + lr];
      b[nf] = bv;
    }
#pragma unroll
    for (int mi = 0; mi < 4; ++mi)
#pragma unroll
      for (int nf = 0; nf < 4; ++nf)
        acc[mi][nf] = __builtin_amdgcn_mfma_f32_16x16x32_bf16(a[mi], b[nf], acc[mi][nf], 0, 0, 0);
    __syncthreads();
  }
#pragma unroll
  for (int mi = 0; mi < 4; ++mi) {
    int m = wm + mi * 16 + lg * 4;
#pragma unroll
    for (int nf = 0; nf < 4; ++nf) {
      int n = nblk + wn + nf * 16 + lr;
      if (n < ST) {
#pragma unroll
        for (int i = 0; i < 4; ++i) {
          float v = (n < NVALID) ? (acc[mi][nf][i] + (float)hz[(size_t)(m + i) * SH + n]) : 0.f;
          t[((size_t)z * SS + m + i) * ST + n] = (bf16)v;
        }
      }
    }
  }
}

// ---------------- dense MFMA: C = relu((X @ Y^T + 2*bias)/denom) ----------------
template<bool F32OUT>
__global__ __launch_bounds__(256) void k_dense(
    const bf16* __restrict__ X, const bf16* __restrict__ Y,
    const float* __restrict__ bias, const float* __restrict__ denom,
    void* __restrict__ Cout, int K, int NVALID, int SC) {
  __shared__ __align__(16) bf16 As[128 * 40];
  __shared__ __align__(16) bf16 Bs[160 * 40];
  int tid = threadIdx.x;
  int mblk = blockIdx.y * 128, nblk = blockIdx.x * 160;
  int wid = tid >> 6, lane = tid & 63;
  int wm = (wid >> 1) * 64, wn = (wid & 1) * 80;
  int lr = lane & 15, lg = lane >> 4;
  f32x4 acc[4][5];
#pragma unroll
  for (int i = 0; i < 4; ++i)
#pragma unroll
    for (int j = 0; j < 5; ++j) acc[i][j] = (f32x4){0.f, 0.f, 0.f, 0.f};
  int rA = tid >> 2, kA = (tid & 3) * 8;
  for (int k0 = 0; k0 < K; k0 += 32) {
#pragma unroll
    for (int it = 0; it < 2; ++it) {
      int r = it * 64 + rA;
      *(bf16x8*)&As[r * 40 + kA] = *(const bf16x8*)&X[(size_t)(mblk + r) * K + k0 + kA];
    }
#pragma unroll
    for (int it = 0; it < 3; ++it) {
      int r = it * 64 + rA;
      if (r < 160)
        *(bf16x8*)&Bs[r * 40 + kA] = *(const bf16x8*)&Y[(size_t)(nblk + r) * K + k0 + kA];
    }
    __syncthreads();
    bf16x8 a[4], b[5];
#pragma unroll
    for (int mi = 0; mi < 4; ++mi)
      a[mi] = *(const bf16x8*)&As[(wm + mi * 16 + lr) * 40 + lg * 8];
#pragma unroll
    for (int nf = 0; nf < 5; ++nf)
      b[nf] = *(const bf16x8*)&Bs[(wn + nf * 16 + lr) * 40 + lg * 8];
#pragma unroll
    for (int mi = 0; mi < 4; ++mi)
#pragma unroll
      for (int nf = 0; nf < 5; ++nf)
        acc[mi][nf] = __builtin_amdgcn_mfma_f32_16x16x32_bf16(a[mi], b[nf], acc[mi][nf], 0, 0, 0);
    __syncthreads();
  }
#pragma unroll
  for (int mi = 0; mi < 4; ++mi) {
    int m0 = mblk + wm + mi * 16 + lg * 4;
    float dn[4];
#pragma unroll
    for (int i = 0; i < 4; ++i) dn[i] = denom[m0 + i];
#pragma unroll
    for (int nf = 0; nf < 5; ++nf) {
      int n = nblk + wn + nf * 16 + lr;
      if (n < NVALID) {
        float bs = 2.f * bias[n];
#pragma unroll
        for (int i = 0; i < 4; ++i) {
          float v = fmaxf((acc[mi][nf][i] + bs) / dn[i], 0.f);
          if (F32OUT) ((float*)Cout)[(size_t)(m0 + i) * SC + n] = v;
          else ((bf16*)Cout)[(size_t)(m0 + i) * SC + n] = (bf16)v;
        }
      }
    }
  }
}

// ---------------- MLP: thread-per-output dot product over transposed weights ----
// C[m,n] = act(sum_k A[m,k]*BT[n,k] + bias[n]); A [M][K], BT [N][K], fp32.
// High parallelism (M*N threads), no barriers; working set is L2-resident.
template<bool RELU, int K, int N>
__global__ __launch_bounds__(256) void k_mlp(
    const float* __restrict__ A, const float* __restrict__ BT,
    const float* __restrict__ bias, float* __restrict__ C, int M) {
  int idx = blockIdx.x * 256 + threadIdx.x;
  if (idx >= M * N) return;
  int m = idx / N, n = idx - m * N;
  const float4* a4 = (const float4*)(A + (size_t)m * K);
  const float4* b4 = (const float4*)(BT + (size_t)n * K);
  float acc = 0.f;
#pragma unroll 8
  for (int i = 0; i < K / 4; ++i) {
    float4 av = a4[i], bv = b4[i];
    acc += av.x * bv.x + av.y * bv.y + av.z * bv.z + av.w * bv.w;
  }
  float v = acc + bias[n];
  if (RELU) v = fmaxf(v, 0.f);
  C[idx] = v;
}

// ---------------- final 3-way masked max pool (h2 fp32) ----------------
__global__ void k_pool(const float* __restrict__ h, const int* __restrict__ pmask,
                       const int* __restrict__ subj_pos, const int* __restrict__ obj_pos,
                       float* __restrict__ cat, float* __restrict__ hout) {
  __shared__ int pm[SS], sm[SS], om[SS];
  int b = blockIdx.x, e = threadIdx.x;  // 320 threads
  if (e < SS) {
    pm[e] = pmask[b * SS + e];
    sm[e] = (subj_pos[b * SS + e] != 0) ? 1 : 0;
    om[e] = (obj_pos[b * SS + e] != 0) ? 1 : 0;
  }
  __syncthreads();
  if (e < DHID) {
    const float* hb = h + (size_t)b * SS * DHID + e;
    float mh = -INF_, ms = -INF_, mo = -INF_;
    for (int s = 0; s < SS; ++s) {
      float v = hb[(size_t)s * DHID];
      if (!pm[s]) mh = fmaxf(mh, v);
      if (!sm[s]) ms = fmaxf(ms, v);
      if (!om[s]) mo = fmaxf(mo, v);
    }
    cat[(size_t)b * 900 + e] = mh;
    cat[(size_t)b * 900 + 300 + e] = ms;
    cat[(size_t)b * 900 + 600 + e] = mo;
    hout[(size_t)b * DHID + e] = mh;
  }
}

extern "C" void kernel_launch(void* const* d_in, const int* in_sizes, int n_in,
                              void* d_out, int out_size, void* d_ws, size_t ws_size,
                              hipStream_t stream) {
  const int* words = (const int*)d_in[0];
  const int* pos = (const int*)d_in[1];
  const int* ner = (const int*)d_in[2];
  const int* deprel = (const int*)d_in[3];
  const int* subj_pos = (const int*)d_in[4];
  const int* obj_pos = (const int*)d_in[5];
  const float* adj = (const float*)d_in[6];
  const float* emb_w = (const float*)d_in[7];
  const float* pos_w = (const float*)d_in[8];
  const float* ner_w = (const float*)d_in[9];
  const float* dep_w = (const float*)d_in[10];
  const float* attn_w = (const float*)d_in[11];
  const float* W0 = (const float*)d_in[12];
  const float* b0 = (const float*)d_in[13];
  const float* W1 = (const float*)d_in[14];
  const float* b1 = (const float*)d_in[15];
  const float* mlp0_w = (const float*)d_in[16];
  const float* mlp0_b = (const float*)d_in[17];
  const float* mlp1_w = (const float*)d_in[18];
  const float* mlp1_b = (const float*)d_in[19];
  const float* cls_w = (const float*)d_in[20];
  const float* cls_b = (const float*)d_in[21];
  float* out = (float*)d_out;

  // -------- workspace carve (~156 MB), liveness reuse --------
  char* w = (char*)d_ws;
  bf16* h0 = (bf16*)w;        // [65536][384] bf16 -> later h1 [65536][320] bf16 -> h2f [65536][300] f32
  bf16* h1 = (bf16*)w;
  float* h2f = (float*)w;
  w += 78643200;
  bf16* t1 = (bf16*)w;        // [65536][384] bf16 -> later t2 [65536][320]
  bf16* t2 = (bf16*)w;
  w += 50331648;
  bf16* amat = (bf16*)w; w += 16777216;   // [512][128][128]
  bf16* W0T = (bf16*)w; w += 294912;      // [384][384]
  bf16* W1T = (bf16*)w; w += 204800;      // [320][320]
  float* denom = (float*)w; w += 262144;
  int* pmask = (int*)w; w += 262144;
  int* dmask = (int*)w; w += 262144;
  float* qa = (float*)w; w += 262144;
  float* wts = (float*)w; w += 262144;
  float* cat = (float*)w; w += 1843200;   // [512][900] f32
  float* m0b = (float*)w; w += 614400;    // [512][300] f32
  float* m1b = (float*)w; w += 614400;    // [512][300] f32
  float* M0T = (float*)w; w += 1080000;   // [300][900] f32
  float* M1T = (float*)w; w += 360000;    // [300][300] f32
  float* CLT = (float*)w; w += 50400;     // [42][300] f32

  k_prepw<<<(384 * 384 + 255) / 256, 256, 0, stream>>>(W0, DIN, DHID, W0T, DINP, DINP);
  k_prepw<<<(320 * 320 + 255) / 256, 256, 0, stream>>>(W1, DHID, DHID, W1T, DHP, DHP);
  k_prepwf<<<(300 * 900 + 255) / 256, 256, 0, stream>>>(mlp0_w, 900, DHID, M0T);
  k_prepwf<<<(300 * 300 + 255) / 256, 256, 0, stream>>>(mlp1_w, DHID, DHID, M1T);
  k_prepwf<<<(42 * 300 + 255) / 256, 256, 0, stream>>>(cls_w, DHID, NCLS, CLT);
  k_degrees<<<NB, SS, 0, stream>>>(adj, denom, pmask, dmask);
  k_embed<<<(NB * SS) / 16, 192, 0, stream>>>(words, pos, ner, emb_w, pos_w, ner_w, h0);
  k_query_qa<<<NB, 384, 0, stream>>>(h0, pmask, attn_w, qa);
  k_weights<<<NB, SS, 0, stream>>>(deprel, dep_w, dmask, qa, wts);
  k_symmetrize<<<NB, 256, 0, stream>>>(adj, wts, amat);

  // Layer 1: t1 = a@h0 + h0   (bf16 MFMA, batched)
  k_ah<<<dim3(3, NB), 256, 0, stream>>>(amat, h0, DINP, DINP, t1, DINP);
  // h1 = relu((t1@W0 + 2*b0)/denom)  -> bf16 [65536][320]
  k_dense<false><<<dim3(2, NB), 256, 0, stream>>>(t1, W0T, b0, denom, h1, DINP, DHID, DHP);
  // Layer 2: t2 = a@h1 + h1
  k_ah<<<dim3(3, NB), 256, 0, stream>>>(amat, h1, DHP, DHID, t2, DHP);
  // h2 = relu((t2@W1 + 2*b1)/denom)  -> fp32 [65536][300]
  k_dense<true><<<dim3(2, NB), 256, 0, stream>>>(t2, W1T, b1, denom, h2f, DHP, DHID, DHID);

  // pools -> cat [512,900]; h_out -> out + NB*NCLS
  k_pool<<<NB, 320, 0, stream>>>(h2f, pmask, subj_pos, obj_pos, cat, out + NB * NCLS);

  // MLP + classifier: thread-per-output fp32 (parallelism fix; was 40-block tiled GEMM)
  k_mlp<true, 900, DHID><<<(NB * DHID + 255) / 256, 256, 0, stream>>>(cat, M0T, mlp0_b, m0b, NB);
  k_mlp<true, DHID, DHID><<<(NB * DHID + 255) / 256, 256, 0, stream>>>(m0b, M1T, mlp1_b, m1b, NB);
  k_mlp<false, DHID, NCLS><<<(NB * NCLS + 255) / 256, 256, 0, stream>>>(m1b, CLT, cls_b, out, NB);
}

// Round 8
// 505.132 us; speedup vs baseline: 2.6944x; 1.2328x over previous
//
#include <hip/hip_runtime.h>
#include <cstdint>

typedef __bf16 bf16;
typedef bf16 bf16x8 __attribute__((ext_vector_type(8)));
typedef float f32x4 __attribute__((ext_vector_type(4)));

#define NB 512     // batch
#define SS 128     // sequence
#define DIN 360    // emb(300)+pos(30)+ner(30)
#define DINP 384   // DIN padded to mult of 32 (zero pad)
#define DHID 300
#define DHP 320    // DHID padded to mult of 32
#define DDEPW 100
#define NCLS 42
#define KCAT 928   // 3*DHID=900 padded to mult of 32

constexpr float INF_ = 1e12f;
constexpr float NEG_ = -1e30f;

// ---------------- degrees / masks / denom (fp32) ----------------
__global__ void k_degrees(const float* __restrict__ adj, float* __restrict__ denom,
                          int* __restrict__ pmask, int* __restrict__ dmask) {
  int b = blockIdx.x, t = threadIdx.x;  // 128 threads
  const float* A = adj + (size_t)b * SS * SS;
  float indeg = 0.f;
  for (int s = 0; s < SS; ++s) indeg += A[s * SS + t];
  float outdeg = 0.f;
  const float4* row = (const float4*)(A + t * SS);
#pragma unroll
  for (int i = 0; i < SS / 4; ++i) { float4 v = row[i]; outdeg += v.x + v.y + v.z + v.w; }
  int idx = b * SS + t;
  denom[idx] = outdeg + 1.f;
  pmask[idx] = ((indeg + outdeg) == 0.f) ? 1 : 0;
  dmask[idx] = (indeg == 0.f) ? 1 : 0;
}

// ---------------- embedding gather -> h0 bf16 [B*S][384], cols 360..383 zero ----
__global__ void k_embed(const int* __restrict__ words, const int* __restrict__ pos,
                        const int* __restrict__ ner,
                        const float* __restrict__ emb_w, const float* __restrict__ pos_w,
                        const float* __restrict__ ner_w, bf16* __restrict__ h) {
  int tid = threadIdx.x;  // 192 threads: 180 data (2 floats each), 12 pad-zero
  int tok0 = blockIdx.x * 16;
  for (int i = 0; i < 16; ++i) {
    int tok = tok0 + i;
    if (tid < 180) {
      int c = tid * 2;
      float2 v;
      if (c < 300)      v = *(const float2*)(emb_w + (size_t)words[tok] * 300 + c);
      else if (c < 330) v = *(const float2*)(pos_w + (size_t)pos[tok] * 30 + (c - 300));
      else              v = *(const float2*)(ner_w + (size_t)ner[tok] * 30 + (c - 330));
      union { bf16 b[2]; uint32_t u; } cvt;
      cvt.b[0] = (bf16)v.x; cvt.b[1] = (bf16)v.y;
      *(uint32_t*)(h + (size_t)tok * DINP + c) = cvt.u;
    } else {
      int c = 360 + (tid - 180) * 2;
      *(uint32_t*)(h + (size_t)tok * DINP + c) = 0u;
    }
  }
}

// ---------------- W [K][N] fp32 -> WT bf16 [RP][SP] zero-padded ----------------
__global__ void k_prepw(const float* __restrict__ W, int K, int N,
                        bf16* __restrict__ WT, int RP, int SP) {
  int idx = blockIdx.x * 256 + threadIdx.x;
  if (idx >= RP * SP) return;
  int r = idx / SP, c = idx % SP;
  float v = (r < N && c < K) ? W[(size_t)c * N + r] : 0.f;
  WT[(size_t)r * SP + c] = (bf16)v;
}

// ---------------- W [K][N] fp32 -> WT bf16 [NP][KP] zero-padded (MLP weights) ----
__global__ void k_prepwb(const float* __restrict__ W, int K, int N,
                         bf16* __restrict__ WT, int KP, int NP) {
  int idx = blockIdx.x * 256 + threadIdx.x;
  if (idx >= NP * KP) return;
  int n = idx / KP, k = idx - n * KP;
  float v = (n < N && k < K) ? W[(size_t)k * N + n] : 0.f;
  WT[(size_t)n * KP + k] = (bf16)v;
}

// ---------------- query = pool_max(h0) ; qa = attn_w @ query ----------------
__global__ void k_query_qa(const bf16* __restrict__ h, const int* __restrict__ pmask,
                           const float* __restrict__ attn_w, float* __restrict__ qa) {
  __shared__ float q[DIN];
  __shared__ int pm[SS];
  int b = blockIdx.x, tid = threadIdx.x;  // 384 threads
  if (tid < SS) pm[tid] = pmask[b * SS + tid];
  __syncthreads();
  if (tid < DIN) {
    float m = -INF_;
    const bf16* hb = h + (size_t)b * SS * DINP + tid;
    for (int s = 0; s < SS; ++s) { float v = (float)hb[(size_t)s * DINP]; if (!pm[s]) m = fmaxf(m, v); }
    q[tid] = m;
  }
  __syncthreads();
  if (tid < DDEPW) {
    const float* wr = attn_w + (size_t)tid * DIN;
    float acc = 0.f;
    for (int e = 0; e < DIN; ++e) acc += wr[e] * q[e];
    qa[b * SS + tid] = acc;
  }
}

// ---------------- scores -> softmax -> weights (fp32) ----------------
__global__ void k_weights(const int* __restrict__ deprel, const float* __restrict__ dep_w,
                          const int* __restrict__ dmask, const float* __restrict__ qa,
                          float* __restrict__ wts) {
  __shared__ float qs[DDEPW];
  __shared__ float red[SS];
  int b = blockIdx.x, s = threadIdx.x;  // 128 threads
  if (s < DDEPW) qs[s] = qa[b * SS + s];
  __syncthreads();
  float score;
  if (dmask[b * SS + s]) score = NEG_;
  else {
    const float* dr = dep_w + (size_t)deprel[b * SS + s] * DDEPW;
    float acc = 0.f;
    for (int d = 0; d < DDEPW; ++d) acc += dr[d] * qs[d];
    score = acc;
  }
  red[s] = score; __syncthreads();
  for (int off = 64; off > 0; off >>= 1) { if (s < off) red[s] = fmaxf(red[s], red[s + off]); __syncthreads(); }
  float mx = red[0]; __syncthreads();
  float ex = expf(score - mx);
  red[s] = ex; __syncthreads();
  for (int off = 64; off > 0; off >>= 1) { if (s < off) red[s] += red[s + off]; __syncthreads(); }
  wts[b * SS + s] = ex / red[0];
}

// ---------------- amat bf16: a[s,t] = adj[s,t]*w[s] + adj[t,s]*w[t] ----------------
__global__ void k_symmetrize(const float* __restrict__ adj, const float* __restrict__ wts,
                             bf16* __restrict__ amat) {
  __shared__ float tile[SS * SS];  // 64 KiB, skewed: (s,t) at [s*128 + ((t+s)&127)]
  int b = blockIdx.x, tid = threadIdx.x;  // 256 threads
  const float* Ab = adj + (size_t)b * SS * SS;
  bf16* ab = amat + (size_t)b * SS * SS;
#pragma unroll 4
  for (int i = 0; i < 64; ++i) {
    int idx = i * 256 + tid;
    int s_ = idx >> 7, t_ = idx & 127;
    tile[(s_ << 7) + ((t_ + s_) & 127)] = Ab[idx];
  }
  __syncthreads();
  const float* wb = wts + b * SS;
#pragma unroll 4
  for (int i = 0; i < 64; ++i) {
    int idx = i * 256 + tid;
    int s_ = idx >> 7, t_ = idx & 127;
    float v = tile[(s_ << 7) + ((t_ + s_) & 127)] * wb[s_]
            + tile[(t_ << 7) + ((s_ + t_) & 127)] * wb[t_];
    ab[idx] = (bf16)v;
  }
}

// ---------------- batched MFMA: t[z] = amat[z] @ h[z] + h[z] ----------------
__global__ __launch_bounds__(256) void k_ah(
    const bf16* __restrict__ amat, const bf16* __restrict__ h,
    int SH, int NVALID, bf16* __restrict__ t, int ST) {
  __shared__ __align__(16) bf16 Xs[128 * 136];
  __shared__ __align__(16) bf16 Ys[32 * 136];
  int z = blockIdx.y;
  int nblk = blockIdx.x * 128;
  int tid = threadIdx.x;
  const bf16* Az = amat + (size_t)z * SS * SS;
  const bf16* hz = h + (size_t)z * SS * SH;
  {  // stage whole 128x128 amat tile (b128, coalesced)
    int c8 = (tid & 15) * 8;
#pragma unroll
    for (int it = 0; it < 8; ++it) {
      int r = it * 16 + (tid >> 4);
      *(bf16x8*)&Xs[r * 136 + c8] = *(const bf16x8*)&Az[r * SS + c8];
    }
  }
  int wid = tid >> 6, lane = tid & 63;
  int wm = (wid >> 1) * 64, wn = (wid & 1) * 64;
  int lr = lane & 15, lg = lane >> 4;
  f32x4 acc[4][4];
#pragma unroll
  for (int i = 0; i < 4; ++i)
#pragma unroll
    for (int j = 0; j < 4; ++j) acc[i][j] = (f32x4){0.f, 0.f, 0.f, 0.f};

  for (int k0 = 0; k0 < SS; k0 += 32) {
    {  // stage Ys = h rows k0..k0+31, cols nblk..nblk+127
      int c8 = (tid & 15) * 8;
      int col = nblk + c8;
#pragma unroll
      for (int it = 0; it < 2; ++it) {
        int r = it * 16 + (tid >> 4);
        bf16x8 v;
        if (col < SH) v = *(const bf16x8*)&hz[(size_t)(k0 + r) * SH + col];
        else { union { uint32_t u[4]; bf16x8 bv; } zz; zz.u[0]=zz.u[1]=zz.u[2]=zz.u[3]=0u; v = zz.bv; }
        *(bf16x8*)&Ys[r * 136 + c8] = v;
      }
    }
    __syncthreads();
    bf16x8 a[4], b[4];
#pragma unroll
    for (int mi = 0; mi < 4; ++mi)
      a[mi] = *(const bf16x8*)&Xs[(wm + mi * 16 + lr) * 136 + k0 + lg * 8];
#pragma unroll
    for (int nf = 0; nf < 4; ++nf) {
      bf16x8 bv;
#pragma unroll
      for (int i = 0; i < 8; ++i) bv[i] = Ys[(lg * 8 + i) * 136 + wn + nf * 16 + lr];
      b[nf] = bv;
    }
#pragma unroll
    for (int mi = 0; mi < 4; ++mi)
#pragma unroll
      for (int nf = 0; nf < 4; ++nf)
        acc[mi][nf] = __builtin_amdgcn_mfma_f32_16x16x32_bf16(a[mi], b[nf], acc[mi][nf], 0, 0, 0);
    __syncthreads();
  }
#pragma unroll
  for (int mi = 0; mi < 4; ++mi) {
    int m = wm + mi * 16 + lg * 4;
#pragma unroll
    for (int nf = 0; nf < 4; ++nf) {
      int n = nblk + wn + nf * 16 + lr;
      if (n < ST) {
#pragma unroll
        for (int i = 0; i < 4; ++i) {
          float v = (n < NVALID) ? (acc[mi][nf][i] + (float)hz[(size_t)(m + i) * SH + n]) : 0.f;
          t[((size_t)z * SS + m + i) * ST + n] = (bf16)v;
        }
      }
    }
  }
}

// ---------------- dense MFMA: C = relu((X @ Y^T + 2*bias)/denom) ----------------
template<bool F32OUT>
__global__ __launch_bounds__(256) void k_dense(
    const bf16* __restrict__ X, const bf16* __restrict__ Y,
    const float* __restrict__ bias, const float* __restrict__ denom,
    void* __restrict__ Cout, int K, int NVALID, int SC) {
  __shared__ __align__(16) bf16 As[128 * 40];
  __shared__ __align__(16) bf16 Bs[160 * 40];
  int tid = threadIdx.x;
  int mblk = blockIdx.y * 128, nblk = blockIdx.x * 160;
  int wid = tid >> 6, lane = tid & 63;
  int wm = (wid >> 1) * 64, wn = (wid & 1) * 80;
  int lr = lane & 15, lg = lane >> 4;
  f32x4 acc[4][5];
#pragma unroll
  for (int i = 0; i < 4; ++i)
#pragma unroll
    for (int j = 0; j < 5; ++j) acc[i][j] = (f32x4){0.f, 0.f, 0.f, 0.f};
  int rA = tid >> 2, kA = (tid & 3) * 8;
  for (int k0 = 0; k0 < K; k0 += 32) {
#pragma unroll
    for (int it = 0; it < 2; ++it) {
      int r = it * 64 + rA;
      *(bf16x8*)&As[r * 40 + kA] = *(const bf16x8*)&X[(size_t)(mblk + r) * K + k0 + kA];
    }
#pragma unroll
    for (int it = 0; it < 3; ++it) {
      int r = it * 64 + rA;
      if (r < 160)
        *(bf16x8*)&Bs[r * 40 + kA] = *(const bf16x8*)&Y[(size_t)(nblk + r) * K + k0 + kA];
    }
    __syncthreads();
    bf16x8 a[4], b[5];
#pragma unroll
    for (int mi = 0; mi < 4; ++mi)
      a[mi] = *(const bf16x8*)&As[(wm + mi * 16 + lr) * 40 + lg * 8];
#pragma unroll
    for (int nf = 0; nf < 5; ++nf)
      b[nf] = *(const bf16x8*)&Bs[(wn + nf * 16 + lr) * 40 + lg * 8];
#pragma unroll
    for (int mi = 0; mi < 4; ++mi)
#pragma unroll
      for (int nf = 0; nf < 5; ++nf)
        acc[mi][nf] = __builtin_amdgcn_mfma_f32_16x16x32_bf16(a[mi], b[nf], acc[mi][nf], 0, 0, 0);
    __syncthreads();
  }
#pragma unroll
  for (int mi = 0; mi < 4; ++mi) {
    int m0 = mblk + wm + mi * 16 + lg * 4;
    float dn[4];
#pragma unroll
    for (int i = 0; i < 4; ++i) dn[i] = denom[m0 + i];
#pragma unroll
    for (int nf = 0; nf < 5; ++nf) {
      int n = nblk + wn + nf * 16 + lr;
      if (n < NVALID) {
        float bs = 2.f * bias[n];
#pragma unroll
        for (int i = 0; i < 4; ++i) {
          float v = fmaxf((acc[mi][nf][i] + bs) / dn[i], 0.f);
          if (F32OUT) ((float*)Cout)[(size_t)(m0 + i) * SC + n] = v;
          else ((bf16*)Cout)[(size_t)(m0 + i) * SC + n] = (bf16)v;
        }
      }
    }
  }
}

// ---------------- MLP via wave-per-16x16-tile MFMA (no LDS, no barriers) --------
// A bf16 [M][KP] row-major K-contig; BT bf16 [NP][KP] (pre-transposed, zero-pad).
// C[m,n] = act(sum_k A[m,k]*BT[n,k] + bias[n]). BF16OUT: write [M][SC] bf16 with
// zeros for NVALID<=n<NP (keeps next layer's K-pads clean); else fp32, gated.
template<bool RELU, bool BF16OUT, int KP, int NP, int NVALID>
__global__ __launch_bounds__(256) void k_mlp_mfma(
    const bf16* __restrict__ A, const bf16* __restrict__ BT,
    const float* __restrict__ bias, void* __restrict__ C, int M, int SC) {
  constexpr int NT = NP / 16;
  int wid = threadIdx.x >> 6, lane = threadIdx.x & 63;
  int wti = blockIdx.x * 4 + wid;
  int mt = wti / NT, nt = wti - mt * NT;
  if (mt * 16 >= M) return;
  int lr = lane & 15, lg = lane >> 4;
  const bf16* Ap = A + (size_t)(mt * 16 + lr) * KP + lg * 8;
  const bf16* Bp = BT + (size_t)(nt * 16 + lr) * KP + lg * 8;
  f32x4 acc = (f32x4){0.f, 0.f, 0.f, 0.f};
#pragma unroll
  for (int k0 = 0; k0 < KP; k0 += 32) {
    bf16x8 a = *(const bf16x8*)(Ap + k0);
    bf16x8 b = *(const bf16x8*)(Bp + k0);
    acc = __builtin_amdgcn_mfma_f32_16x16x32_bf16(a, b, acc, 0, 0, 0);
  }
  int n = nt * 16 + lr;
  int m0 = mt * 16 + lg * 4;
  float bs = (n < NVALID) ? bias[n] : 0.f;
  if (BF16OUT) {
#pragma unroll
    for (int i = 0; i < 4; ++i) {
      float v = 0.f;
      if (n < NVALID) { v = acc[i] + bs; if (RELU) v = fmaxf(v, 0.f); }
      ((bf16*)C)[(size_t)(m0 + i) * SC + n] = (bf16)v;
    }
  } else {
    if (n < NVALID) {
#pragma unroll
      for (int i = 0; i < 4; ++i) {
        float v = acc[i] + bs;
        if (RELU) v = fmaxf(v, 0.f);
        ((float*)C)[(size_t)(m0 + i) * SC + n] = v;
      }
    }
  }
}

// ---------------- final 3-way masked max pool -> bf16 cat [B][928] + fp32 h_out --
__global__ void k_pool(const float* __restrict__ h, const int* __restrict__ pmask,
                       const int* __restrict__ subj_pos, const int* __restrict__ obj_pos,
                       bf16* __restrict__ catb, float* __restrict__ hout) {
  __shared__ int pm[SS], sm[SS], om[SS];
  int b = blockIdx.x, e = threadIdx.x;  // 384 threads
  if (e < SS) {
    pm[e] = pmask[b * SS + e];
    sm[e] = (subj_pos[b * SS + e] != 0) ? 1 : 0;
    om[e] = (obj_pos[b * SS + e] != 0) ? 1 : 0;
  }
  __syncthreads();
  if (e < DHID) {
    const float* hb = h + (size_t)b * SS * DHID + e;
    float mh = -INF_, ms = -INF_, mo = -INF_;
    for (int s = 0; s < SS; ++s) {
      float v = hb[(size_t)s * DHID];
      if (!pm[s]) mh = fmaxf(mh, v);
      if (!sm[s]) ms = fmaxf(ms, v);
      if (!om[s]) mo = fmaxf(mo, v);
    }
    catb[(size_t)b * KCAT + e] = (bf16)mh;
    catb[(size_t)b * KCAT + 300 + e] = (bf16)ms;
    catb[(size_t)b * KCAT + 600 + e] = (bf16)mo;
    hout[(size_t)b * DHID + e] = mh;
  } else if (e < DHID + (KCAT - 3 * DHID)) {  // zero cols 900..927
    catb[(size_t)b * KCAT + 600 + e] = (bf16)0.f;
  }
}

extern "C" void kernel_launch(void* const* d_in, const int* in_sizes, int n_in,
                              void* d_out, int out_size, void* d_ws, size_t ws_size,
                              hipStream_t stream) {
  const int* words = (const int*)d_in[0];
  const int* pos = (const int*)d_in[1];
  const int* ner = (const int*)d_in[2];
  const int* deprel = (const int*)d_in[3];
  const int* subj_pos = (const int*)d_in[4];
  const int* obj_pos = (const int*)d_in[5];
  const float* adj = (const float*)d_in[6];
  const float* emb_w = (const float*)d_in[7];
  const float* pos_w = (const float*)d_in[8];
  const float* ner_w = (const float*)d_in[9];
  const float* dep_w = (const float*)d_in[10];
  const float* attn_w = (const float*)d_in[11];
  const float* W0 = (const float*)d_in[12];
  const float* b0 = (const float*)d_in[13];
  const float* W1 = (const float*)d_in[14];
  const float* b1 = (const float*)d_in[15];
  const float* mlp0_w = (const float*)d_in[16];
  const float* mlp0_b = (const float*)d_in[17];
  const float* mlp1_w = (const float*)d_in[18];
  const float* mlp1_b = (const float*)d_in[19];
  const float* cls_w = (const float*)d_in[20];
  const float* cls_b = (const float*)d_in[21];
  float* out = (float*)d_out;

  // -------- workspace carve (~148 MB), liveness reuse --------
  char* w = (char*)d_ws;
  bf16* h0 = (bf16*)w;        // [65536][384] bf16 -> later h1 [65536][320] bf16 -> h2f [65536][300] f32
  bf16* h1 = (bf16*)w;
  float* h2f = (float*)w;
  w += 78643200;
  bf16* t1 = (bf16*)w;        // [65536][384] bf16 -> later t2 [65536][320]
  bf16* t2 = (bf16*)w;
  w += 50331648;
  bf16* amat = (bf16*)w; w += 16777216;   // [512][128][128]
  bf16* W0T = (bf16*)w; w += 294912;      // [384][384]
  bf16* W1T = (bf16*)w; w += 204800;      // [320][320]
  float* denom = (float*)w; w += 262144;
  int* pmask = (int*)w; w += 262144;
  int* dmask = (int*)w; w += 262144;
  float* qa = (float*)w; w += 262144;
  float* wts = (float*)w; w += 262144;
  bf16* catb = (bf16*)w; w += 950272;     // [512][928] bf16
  bf16* m0b = (bf16*)w; w += 327680;      // [512][320] bf16
  bf16* m1b = (bf16*)w; w += 327680;      // [512][320] bf16
  bf16* M0T = (bf16*)w; w += 593920;      // [320][928] bf16
  bf16* M1T = (bf16*)w; w += 204800;      // [320][320] bf16
  bf16* CLT = (bf16*)w; w += 30720;       // [48][320] bf16

  k_prepw<<<(384 * 384 + 255) / 256, 256, 0, stream>>>(W0, DIN, DHID, W0T, DINP, DINP);
  k_prepw<<<(320 * 320 + 255) / 256, 256, 0, stream>>>(W1, DHID, DHID, W1T, DHP, DHP);
  k_prepwb<<<(320 * 928 + 255) / 256, 256, 0, stream>>>(mlp0_w, 900, DHID, M0T, KCAT, DHP);
  k_prepwb<<<(320 * 320 + 255) / 256, 256, 0, stream>>>(mlp1_w, DHID, DHID, M1T, DHP, DHP);
  k_prepwb<<<(48 * 320 + 255) / 256, 256, 0, stream>>>(cls_w, DHID, NCLS, CLT, DHP, 48);
  k_degrees<<<NB, SS, 0, stream>>>(adj, denom, pmask, dmask);
  k_embed<<<(NB * SS) / 16, 192, 0, stream>>>(words, pos, ner, emb_w, pos_w, ner_w, h0);
  k_query_qa<<<NB, 384, 0, stream>>>(h0, pmask, attn_w, qa);
  k_weights<<<NB, SS, 0, stream>>>(deprel, dep_w, dmask, qa, wts);
  k_symmetrize<<<NB, 256, 0, stream>>>(adj, wts, amat);

  // Layer 1: t1 = a@h0 + h0   (bf16 MFMA, batched)
  k_ah<<<dim3(3, NB), 256, 0, stream>>>(amat, h0, DINP, DINP, t1, DINP);
  // h1 = relu((t1@W0 + 2*b0)/denom)  -> bf16 [65536][320]
  k_dense<false><<<dim3(2, NB), 256, 0, stream>>>(t1, W0T, b0, denom, h1, DINP, DHID, DHP);
  // Layer 2: t2 = a@h1 + h1
  k_ah<<<dim3(3, NB), 256, 0, stream>>>(amat, h1, DHP, DHID, t2, DHP);
  // h2 = relu((t2@W1 + 2*b1)/denom)  -> fp32 [65536][300]
  k_dense<true><<<dim3(2, NB), 256, 0, stream>>>(t2, W1T, b1, denom, h2f, DHP, DHID, DHID);

  // pools -> catb bf16 [512][928] (zero-padded); h_out fp32 -> out + NB*NCLS
  k_pool<<<NB, 384, 0, stream>>>(h2f, pmask, subj_pos, obj_pos, catb, out + NB * NCLS);

  // MLP + classifier: wave-per-tile MFMA (fixes k_mlp latency wall: 103us @ 5% VALU)
  k_mlp_mfma<true, true, KCAT, DHP, DHID><<<(512 / 16) * (DHP / 16) / 4, 256, 0, stream>>>(
      catb, M0T, mlp0_b, m0b, NB, DHP);
  k_mlp_mfma<true, true, DHP, DHP, DHID><<<(512 / 16) * (DHP / 16) / 4, 256, 0, stream>>>(
      m0b, M1T, mlp1_b, m1b, NB, DHP);
  k_mlp_mfma<false, false, DHP, 48, NCLS><<<(512 / 16) * (48 / 16) / 4, 256, 0, stream>>>(
      m1b, CLT, cls_b, out, NB, NCLS);
}

// Round 9
// 469.673 us; speedup vs baseline: 2.8978x; 1.0755x over previous
//
#include <hip/hip_runtime.h>
#include <cstdint>

typedef __bf16 bf16;
typedef bf16 bf16x8 __attribute__((ext_vector_type(8)));
typedef float f32x4 __attribute__((ext_vector_type(4)));

#define NB 512     // batch
#define SS 128     // sequence
#define DIN 360    // emb(300)+pos(30)+ner(30)
#define DINP 384   // DIN padded to mult of 32 (zero pad)
#define DHID 300
#define DHP 320    // DHID padded to mult of 32
#define DDEPW 100
#define NCLS 42
#define KCAT 928   // 3*DHID=900 padded to mult of 32

constexpr float INF_ = 1e12f;
constexpr float NEG_ = -1e30f;

// async 16B global->LDS; lds dest must be wave-uniform base (+lane*16 implicit)
__device__ __forceinline__ void gload16(const void* g, void* l) {
  __builtin_amdgcn_global_load_lds((const __attribute__((address_space(1))) void*)g,
                                   (__attribute__((address_space(3))) void*)l, 16, 0, 0);
}

// ---------------- degrees / masks / denom (fp32) ----------------
__global__ void k_degrees(const float* __restrict__ adj, float* __restrict__ denom,
                          int* __restrict__ pmask, int* __restrict__ dmask) {
  int b = blockIdx.x, t = threadIdx.x;  // 128 threads
  const float* A = adj + (size_t)b * SS * SS;
  float indeg = 0.f;
  for (int s = 0; s < SS; ++s) indeg += A[s * SS + t];
  float outdeg = 0.f;
  const float4* row = (const float4*)(A + t * SS);
#pragma unroll
  for (int i = 0; i < SS / 4; ++i) { float4 v = row[i]; outdeg += v.x + v.y + v.z + v.w; }
  int idx = b * SS + t;
  denom[idx] = outdeg + 1.f;
  pmask[idx] = ((indeg + outdeg) == 0.f) ? 1 : 0;
  dmask[idx] = (indeg == 0.f) ? 1 : 0;
}

// ---------------- embedding gather -> h0 bf16 [B*S][384], cols 360..383 zero ----
__global__ void k_embed(const int* __restrict__ words, const int* __restrict__ pos,
                        const int* __restrict__ ner,
                        const float* __restrict__ emb_w, const float* __restrict__ pos_w,
                        const float* __restrict__ ner_w, bf16* __restrict__ h) {
  int tid = threadIdx.x;  // 192 threads: 180 data (2 floats each), 12 pad-zero
  int tok0 = blockIdx.x * 16;
  for (int i = 0; i < 16; ++i) {
    int tok = tok0 + i;
    if (tid < 180) {
      int c = tid * 2;
      float2 v;
      if (c < 300)      v = *(const float2*)(emb_w + (size_t)words[tok] * 300 + c);
      else if (c < 330) v = *(const float2*)(pos_w + (size_t)pos[tok] * 30 + (c - 300));
      else              v = *(const float2*)(ner_w + (size_t)ner[tok] * 30 + (c - 330));
      union { bf16 b[2]; uint32_t u; } cvt;
      cvt.b[0] = (bf16)v.x; cvt.b[1] = (bf16)v.y;
      *(uint32_t*)(h + (size_t)tok * DINP + c) = cvt.u;
    } else {
      int c = 360 + (tid - 180) * 2;
      *(uint32_t*)(h + (size_t)tok * DINP + c) = 0u;
    }
  }
}

// ---------------- W [K][N] fp32 -> WT bf16 [RP][SP] zero-padded ----------------
__global__ void k_prepw(const float* __restrict__ W, int K, int N,
                        bf16* __restrict__ WT, int RP, int SP) {
  int idx = blockIdx.x * 256 + threadIdx.x;
  if (idx >= RP * SP) return;
  int r = idx / SP, c = idx % SP;
  float v = (r < N && c < K) ? W[(size_t)c * N + r] : 0.f;
  WT[(size_t)r * SP + c] = (bf16)v;
}

// ---------------- W [K][N] fp32 -> WT bf16 [NP][KP] zero-padded (MLP weights) ----
__global__ void k_prepwb(const float* __restrict__ W, int K, int N,
                         bf16* __restrict__ WT, int KP, int NP) {
  int idx = blockIdx.x * 256 + threadIdx.x;
  if (idx >= NP * KP) return;
  int n = idx / KP, k = idx - n * KP;
  float v = (n < N && k < K) ? W[(size_t)k * N + n] : 0.f;
  WT[(size_t)n * KP + k] = (bf16)v;
}

// ---------------- query = pool_max(h0) ; qa = attn_w @ query ----------------
__global__ void k_query_qa(const bf16* __restrict__ h, const int* __restrict__ pmask,
                           const float* __restrict__ attn_w, float* __restrict__ qa) {
  __shared__ float q[DIN];
  __shared__ int pm[SS];
  int b = blockIdx.x, tid = threadIdx.x;  // 384 threads
  if (tid < SS) pm[tid] = pmask[b * SS + tid];
  __syncthreads();
  if (tid < DIN) {
    float m = -INF_;
    const bf16* hb = h + (size_t)b * SS * DINP + tid;
    for (int s = 0; s < SS; ++s) { float v = (float)hb[(size_t)s * DINP]; if (!pm[s]) m = fmaxf(m, v); }
    q[tid] = m;
  }
  __syncthreads();
  if (tid < DDEPW) {
    const float* wr = attn_w + (size_t)tid * DIN;
    float acc = 0.f;
    for (int e = 0; e < DIN; ++e) acc += wr[e] * q[e];
    qa[b * SS + tid] = acc;
  }
}

// ---------------- scores -> softmax -> weights (fp32) ----------------
__global__ void k_weights(const int* __restrict__ deprel, const float* __restrict__ dep_w,
                          const int* __restrict__ dmask, const float* __restrict__ qa,
                          float* __restrict__ wts) {
  __shared__ float qs[DDEPW];
  __shared__ float red[SS];
  int b = blockIdx.x, s = threadIdx.x;  // 128 threads
  if (s < DDEPW) qs[s] = qa[b * SS + s];
  __syncthreads();
  float score;
  if (dmask[b * SS + s]) score = NEG_;
  else {
    const float* dr = dep_w + (size_t)deprel[b * SS + s] * DDEPW;
    float acc = 0.f;
    for (int d = 0; d < DDEPW; ++d) acc += dr[d] * qs[d];
    score = acc;
  }
  red[s] = score; __syncthreads();
  for (int off = 64; off > 0; off >>= 1) { if (s < off) red[s] = fmaxf(red[s], red[s + off]); __syncthreads(); }
  float mx = red[0]; __syncthreads();
  float ex = expf(score - mx);
  red[s] = ex; __syncthreads();
  for (int off = 64; off > 0; off >>= 1) { if (s < off) red[s] += red[s + off]; __syncthreads(); }
  wts[b * SS + s] = ex / red[0];
}

// ---------------- amat bf16: a[s,t] = adj[s,t]*w[s] + adj[t,s]*w[t] ----------------
__global__ void k_symmetrize(const float* __restrict__ adj, const float* __restrict__ wts,
                             bf16* __restrict__ amat) {
  __shared__ float tile[SS * SS];  // 64 KiB, skewed: (s,t) at [s*128 + ((t+s)&127)]
  int b = blockIdx.x, tid = threadIdx.x;  // 256 threads
  const float* Ab = adj + (size_t)b * SS * SS;
  bf16* ab = amat + (size_t)b * SS * SS;
#pragma unroll 4
  for (int i = 0; i < 64; ++i) {
    int idx = i * 256 + tid;
    int s_ = idx >> 7, t_ = idx & 127;
    tile[(s_ << 7) + ((t_ + s_) & 127)] = Ab[idx];
  }
  __syncthreads();
  const float* wb = wts + b * SS;
#pragma unroll 4
  for (int i = 0; i < 64; ++i) {
    int idx = i * 256 + tid;
    int s_ = idx >> 7, t_ = idx & 127;
    float v = tile[(s_ << 7) + ((t_ + s_) & 127)] * wb[s_]
            + tile[(t_ << 7) + ((s_ + t_) & 127)] * wb[t_];
    ab[idx] = (bf16)v;
  }
}

// ---------------- batched MFMA: t[z] = amat[z] @ h[z] + h[z] ----------------
__global__ __launch_bounds__(256) void k_ah(
    const bf16* __restrict__ amat, const bf16* __restrict__ h,
    int SH, int NVALID, bf16* __restrict__ t, int ST) {
  __shared__ __align__(16) bf16 Xs[128 * 136];
  __shared__ __align__(16) bf16 Ys[32 * 136];
  int z = blockIdx.y;
  int nblk = blockIdx.x * 128;
  int tid = threadIdx.x;
  const bf16* Az = amat + (size_t)z * SS * SS;
  const bf16* hz = h + (size_t)z * SS * SH;
  {  // stage whole 128x128 amat tile (b128, coalesced)
    int c8 = (tid & 15) * 8;
#pragma unroll
    for (int it = 0; it < 8; ++it) {
      int r = it * 16 + (tid >> 4);
      *(bf16x8*)&Xs[r * 136 + c8] = *(const bf16x8*)&Az[r * SS + c8];
    }
  }
  int wid = tid >> 6, lane = tid & 63;
  int wm = (wid >> 1) * 64, wn = (wid & 1) * 64;
  int lr = lane & 15, lg = lane >> 4;
  f32x4 acc[4][4];
#pragma unroll
  for (int i = 0; i < 4; ++i)
#pragma unroll
    for (int j = 0; j < 4; ++j) acc[i][j] = (f32x4){0.f, 0.f, 0.f, 0.f};

  for (int k0 = 0; k0 < SS; k0 += 32) {
    {  // stage Ys = h rows k0..k0+31, cols nblk..nblk+127
      int c8 = (tid & 15) * 8;
      int col = nblk + c8;
#pragma unroll
      for (int it = 0; it < 2; ++it) {
        int r = it * 16 + (tid >> 4);
        bf16x8 v;
        if (col < SH) v = *(const bf16x8*)&hz[(size_t)(k0 + r) * SH + col];
        else { union { uint32_t u[4]; bf16x8 bv; } zz; zz.u[0]=zz.u[1]=zz.u[2]=zz.u[3]=0u; v = zz.bv; }
        *(bf16x8*)&Ys[r * 136 + c8] = v;
      }
    }
    __syncthreads();
    bf16x8 a[4], b[4];
#pragma unroll
    for (int mi = 0; mi < 4; ++mi)
      a[mi] = *(const bf16x8*)&Xs[(wm + mi * 16 + lr) * 136 + k0 + lg * 8];
#pragma unroll
    for (int nf = 0; nf < 4; ++nf) {
      bf16x8 bv;
#pragma unroll
      for (int i = 0; i < 8; ++i) bv[i] = Ys[(lg * 8 + i) * 136 + wn + nf * 16 + lr];
      b[nf] = bv;
    }
#pragma unroll
    for (int mi = 0; mi < 4; ++mi)
#pragma unroll
      for (int nf = 0; nf < 4; ++nf)
        acc[mi][nf] = __builtin_amdgcn_mfma_f32_16x16x32_bf16(a[mi], b[nf], acc[mi][nf], 0, 0, 0);
    __syncthreads();
  }
#pragma unroll
  for (int mi = 0; mi < 4; ++mi) {
    int m = wm + mi * 16 + lg * 4;
#pragma unroll
    for (int nf = 0; nf < 4; ++nf) {
      int n = nblk + wn + nf * 16 + lr;
      if (n < ST) {
#pragma unroll
        for (int i = 0; i < 4; ++i) {
          float v = (n < NVALID) ? (acc[mi][nf][i] + (float)hz[(size_t)(m + i) * SH + n]) : 0.f;
          t[((size_t)z * SS + m + i) * ST + n] = (bf16)v;
        }
      }
    }
  }
}

// ---------------- dense MFMA v2: C = relu((X @ Y^T + 2*bias)/denom) ----------------
// BM=128 BN=160 BK=64; global_load_lds(16B) staging into XOR-swizzled linear LDS.
// LDS layout: elem(row,k-grp kg of 8) at row*64 + ((kg ^ (row&7))*8)  [128B rows]
// Staging lane-load j: row=j>>3, slot=j&7 -> source kg = slot ^ (row&7).
template<bool F32OUT>
__global__ __launch_bounds__(256, 4) void k_dense(
    const bf16* __restrict__ X, const bf16* __restrict__ Y,
    const float* __restrict__ bias, const float* __restrict__ denom,
    void* __restrict__ Cout, int K, int NVALID, int SC) {
  __shared__ __align__(16) bf16 As[128 * 64];  // 16 KB
  __shared__ __align__(16) bf16 Bs[160 * 64];  // 20 KB
  int tid = threadIdx.x;
  int mblk = blockIdx.y * 128, nblk = blockIdx.x * 160;
  int wid = tid >> 6, lane = tid & 63;
  int wm = (wid >> 1) * 64, wn = (wid & 1) * 80;
  int lr = lane & 15, lg = lane >> 4;
  int srow = tid >> 3, slot = tid & 7;  // staging decode
  f32x4 acc[4][5];
#pragma unroll
  for (int i = 0; i < 4; ++i)
#pragma unroll
    for (int j = 0; j < 5; ++j) acc[i][j] = (f32x4){0.f, 0.f, 0.f, 0.f};

  for (int k0 = 0; k0 < K; k0 += 64) {
    __syncthreads();  // previous iter's LDS reads complete before overwrite
#pragma unroll
    for (int it = 0; it < 4; ++it) {  // A: 128 rows x 64 cols
      int row = it * 32 + srow;
      int kg = slot ^ (row & 7);
      gload16(&X[(size_t)(mblk + row) * K + k0 + kg * 8], &As[(it * 256 + wid * 64) * 8]);
    }
#pragma unroll
    for (int it = 0; it < 5; ++it) {  // B: 160 rows x 64 cols
      int row = it * 32 + srow;
      int kg = slot ^ (row & 7);
      gload16(&Y[(size_t)(nblk + row) * K + k0 + kg * 8], &Bs[(it * 256 + wid * 64) * 8]);
    }
    __syncthreads();  // vmcnt drained -> tiles ready
#pragma unroll
    for (int kk = 0; kk < 2; ++kk) {
      bf16x8 a[4], b[5];
#pragma unroll
      for (int mi = 0; mi < 4; ++mi) {
        int r = wm + mi * 16 + lr;
        a[mi] = *(const bf16x8*)&As[r * 64 + (((kk * 4 + lg) ^ (lr & 7)) * 8)];
      }
#pragma unroll
      for (int nf = 0; nf < 5; ++nf) {
        int r = wn + nf * 16 + lr;
        b[nf] = *(const bf16x8*)&Bs[r * 64 + (((kk * 4 + lg) ^ (lr & 7)) * 8)];
      }
#pragma unroll
      for (int mi = 0; mi < 4; ++mi)
#pragma unroll
        for (int nf = 0; nf < 5; ++nf)
          acc[mi][nf] = __builtin_amdgcn_mfma_f32_16x16x32_bf16(a[mi], b[nf], acc[mi][nf], 0, 0, 0);
    }
  }
#pragma unroll
  for (int mi = 0; mi < 4; ++mi) {
    int m0 = mblk + wm + mi * 16 + lg * 4;
    float dn[4];
#pragma unroll
    for (int i = 0; i < 4; ++i) dn[i] = denom[m0 + i];
#pragma unroll
    for (int nf = 0; nf < 5; ++nf) {
      int n = nblk + wn + nf * 16 + lr;
      if (n < NVALID) {
        float bs = 2.f * bias[n];
#pragma unroll
        for (int i = 0; i < 4; ++i) {
          float v = fmaxf((acc[mi][nf][i] + bs) / dn[i], 0.f);
          if (F32OUT) ((float*)Cout)[(size_t)(m0 + i) * SC + n] = v;
          else ((bf16*)Cout)[(size_t)(m0 + i) * SC + n] = (bf16)v;
        }
      }
    }
  }
}

// ---------------- MLP via wave-per-16x16-tile MFMA (no LDS, no barriers) --------
template<bool RELU, bool BF16OUT, int KP, int NP, int NVALID>
__global__ __launch_bounds__(256) void k_mlp_mfma(
    const bf16* __restrict__ A, const bf16* __restrict__ BT,
    const float* __restrict__ bias, void* __restrict__ C, int M, int SC) {
  constexpr int NT = NP / 16;
  int wid = threadIdx.x >> 6, lane = threadIdx.x & 63;
  int wti = blockIdx.x * 4 + wid;
  int mt = wti / NT, nt = wti - mt * NT;
  if (mt * 16 >= M) return;
  int lr = lane & 15, lg = lane >> 4;
  const bf16* Ap = A + (size_t)(mt * 16 + lr) * KP + lg * 8;
  const bf16* Bp = BT + (size_t)(nt * 16 + lr) * KP + lg * 8;
  f32x4 acc = (f32x4){0.f, 0.f, 0.f, 0.f};
#pragma unroll
  for (int k0 = 0; k0 < KP; k0 += 32) {
    bf16x8 a = *(const bf16x8*)(Ap + k0);
    bf16x8 b = *(const bf16x8*)(Bp + k0);
    acc = __builtin_amdgcn_mfma_f32_16x16x32_bf16(a, b, acc, 0, 0, 0);
  }
  int n = nt * 16 + lr;
  int m0 = mt * 16 + lg * 4;
  float bs = (n < NVALID) ? bias[n] : 0.f;
  if (BF16OUT) {
#pragma unroll
    for (int i = 0; i < 4; ++i) {
      float v = 0.f;
      if (n < NVALID) { v = acc[i] + bs; if (RELU) v = fmaxf(v, 0.f); }
      ((bf16*)C)[(size_t)(m0 + i) * SC + n] = (bf16)v;
    }
  } else {
    if (n < NVALID) {
#pragma unroll
      for (int i = 0; i < 4; ++i) {
        float v = acc[i] + bs;
        if (RELU) v = fmaxf(v, 0.f);
        ((float*)C)[(size_t)(m0 + i) * SC + n] = v;
      }
    }
  }
}

// ---------------- final 3-way masked max pool -> bf16 cat [B][928] + fp32 h_out --
__global__ void k_pool(const float* __restrict__ h, const int* __restrict__ pmask,
                       const int* __restrict__ subj_pos, const int* __restrict__ obj_pos,
                       bf16* __restrict__ catb, float* __restrict__ hout) {
  __shared__ int pm[SS], sm[SS], om[SS];
  int b = blockIdx.x, e = threadIdx.x;  // 384 threads
  if (e < SS) {
    pm[e] = pmask[b * SS + e];
    sm[e] = (subj_pos[b * SS + e] != 0) ? 1 : 0;
    om[e] = (obj_pos[b * SS + e] != 0) ? 1 : 0;
  }
  __syncthreads();
  if (e < DHID) {
    const float* hb = h + (size_t)b * SS * DHID + e;
    float mh = -INF_, ms = -INF_, mo = -INF_;
    for (int s = 0; s < SS; ++s) {
      float v = hb[(size_t)s * DHID];
      if (!pm[s]) mh = fmaxf(mh, v);
      if (!sm[s]) ms = fmaxf(ms, v);
      if (!om[s]) mo = fmaxf(mo, v);
    }
    catb[(size_t)b * KCAT + e] = (bf16)mh;
    catb[(size_t)b * KCAT + 300 + e] = (bf16)ms;
    catb[(size_t)b * KCAT + 600 + e] = (bf16)mo;
    hout[(size_t)b * DHID + e] = mh;
  } else if (e < DHID + (KCAT - 3 * DHID)) {  // zero cols 900..927
    catb[(size_t)b * KCAT + 600 + e] = (bf16)0.f;
  }
}

extern "C" void kernel_launch(void* const* d_in, const int* in_sizes, int n_in,
                              void* d_out, int out_size, void* d_ws, size_t ws_size,
                              hipStream_t stream) {
  const int* words = (const int*)d_in[0];
  const int* pos = (const int*)d_in[1];
  const int* ner = (const int*)d_in[2];
  const int* deprel = (const int*)d_in[3];
  const int* subj_pos = (const int*)d_in[4];
  const int* obj_pos = (const int*)d_in[5];
  const float* adj = (const float*)d_in[6];
  const float* emb_w = (const float*)d_in[7];
  const float* pos_w = (const float*)d_in[8];
  const float* ner_w = (const float*)d_in[9];
  const float* dep_w = (const float*)d_in[10];
  const float* attn_w = (const float*)d_in[11];
  const float* W0 = (const float*)d_in[12];
  const float* b0 = (const float*)d_in[13];
  const float* W1 = (const float*)d_in[14];
  const float* b1 = (const float*)d_in[15];
  const float* mlp0_w = (const float*)d_in[16];
  const float* mlp0_b = (const float*)d_in[17];
  const float* mlp1_w = (const float*)d_in[18];
  const float* mlp1_b = (const float*)d_in[19];
  const float* cls_w = (const float*)d_in[20];
  const float* cls_b = (const float*)d_in[21];
  float* out = (float*)d_out;

  // -------- workspace carve (~148 MB), liveness reuse --------
  char* w = (char*)d_ws;
  bf16* h0 = (bf16*)w;        // [65536][384] bf16 -> later h1 [65536][320] bf16 -> h2f [65536][300] f32
  bf16* h1 = (bf16*)w;
  float* h2f = (float*)w;
  w += 78643200;
  bf16* t1 = (bf16*)w;        // [65536][384] bf16 -> later t2 [65536][320]
  bf16* t2 = (bf16*)w;
  w += 50331648;
  bf16* amat = (bf16*)w; w += 16777216;   // [512][128][128]
  bf16* W0T = (bf16*)w; w += 294912;      // [384][384]
  bf16* W1T = (bf16*)w; w += 204800;      // [320][320]
  float* denom = (float*)w; w += 262144;
  int* pmask = (int*)w; w += 262144;
  int* dmask = (int*)w; w += 262144;
  float* qa = (float*)w; w += 262144;
  float* wts = (float*)w; w += 262144;
  bf16* catb = (bf16*)w; w += 950272;     // [512][928] bf16
  bf16* m0b = (bf16*)w; w += 327680;      // [512][320] bf16
  bf16* m1b = (bf16*)w; w += 327680;      // [512][320] bf16
  bf16* M0T = (bf16*)w; w += 593920;      // [320][928] bf16
  bf16* M1T = (bf16*)w; w += 204800;      // [320][320] bf16
  bf16* CLT = (bf16*)w; w += 30720;       // [48][320] bf16

  k_prepw<<<(384 * 384 + 255) / 256, 256, 0, stream>>>(W0, DIN, DHID, W0T, DINP, DINP);
  k_prepw<<<(320 * 320 + 255) / 256, 256, 0, stream>>>(W1, DHID, DHID, W1T, DHP, DHP);
  k_prepwb<<<(320 * 928 + 255) / 256, 256, 0, stream>>>(mlp0_w, 900, DHID, M0T, KCAT, DHP);
  k_prepwb<<<(320 * 320 + 255) / 256, 256, 0, stream>>>(mlp1_w, DHID, DHID, M1T, DHP, DHP);
  k_prepwb<<<(48 * 320 + 255) / 256, 256, 0, stream>>>(cls_w, DHID, NCLS, CLT, DHP, 48);
  k_degrees<<<NB, SS, 0, stream>>>(adj, denom, pmask, dmask);
  k_embed<<<(NB * SS) / 16, 192, 0, stream>>>(words, pos, ner, emb_w, pos_w, ner_w, h0);
  k_query_qa<<<NB, 384, 0, stream>>>(h0, pmask, attn_w, qa);
  k_weights<<<NB, SS, 0, stream>>>(deprel, dep_w, dmask, qa, wts);
  k_symmetrize<<<NB, 256, 0, stream>>>(adj, wts, amat);

  // Layer 1: t1 = a@h0 + h0   (bf16 MFMA, batched)
  k_ah<<<dim3(3, NB), 256, 0, stream>>>(amat, h0, DINP, DINP, t1, DINP);
  // h1 = relu((t1@W0 + 2*b0)/denom)  -> bf16 [65536][320]
  k_dense<false><<<dim3(2, NB), 256, 0, stream>>>(t1, W0T, b0, denom, h1, DINP, DHID, DHP);
  // Layer 2: t2 = a@h1 + h1
  k_ah<<<dim3(3, NB), 256, 0, stream>>>(amat, h1, DHP, DHID, t2, DHP);
  // h2 = relu((t2@W1 + 2*b1)/denom)  -> fp32 [65536][300]
  k_dense<true><<<dim3(2, NB), 256, 0, stream>>>(t2, W1T, b1, denom, h2f, DHP, DHID, DHID);

  // pools -> catb bf16 [512][928] (zero-padded); h_out fp32 -> out + NB*NCLS
  k_pool<<<NB, 384, 0, stream>>>(h2f, pmask, subj_pos, obj_pos, catb, out + NB * NCLS);

  // MLP + classifier: wave-per-tile MFMA
  k_mlp_mfma<true, true, KCAT, DHP, DHID><<<(512 / 16) * (DHP / 16) / 4, 256, 0, stream>>>(
      catb, M0T, mlp0_b, m0b, NB, DHP);
  k_mlp_mfma<true, true, DHP, DHP, DHID><<<(512 / 16) * (DHP / 16) / 4, 256, 0, stream>>>(
      m0b, M1T, mlp1_b, m1b, NB, DHP);
  k_mlp_mfma<false, false, DHP, 48, NCLS><<<(512 / 16) * (48 / 16) / 4, 256, 0, stream>>>(
      m1b, CLT, cls_b, out, NB, NCLS);
}

// Round 10
// 432.530 us; speedup vs baseline: 3.1466x; 1.0859x over previous
//
#include <hip/hip_runtime.h>
#include <cstdint>

typedef __bf16 bf16;
typedef bf16 bf16x8 __attribute__((ext_vector_type(8)));
typedef float f32x4 __attribute__((ext_vector_type(4)));

#define NB 512     // batch
#define SS 128     // sequence
#define DIN 360    // emb(300)+pos(30)+ner(30)
#define DINP 384   // DIN padded to mult of 32 (zero pad)
#define DHID 300
#define DHP 320    // DHID padded to mult of 32
#define DDEPW 100
#define NCLS 42
#define KCAT 928   // 3*DHID=900 padded to mult of 32

constexpr float INF_ = 1e12f;
constexpr float NEG_ = -1e30f;

// async 16B global->LDS; lds dest is wave-uniform base (+lane*16 implicit)
__device__ __forceinline__ void gload16(const void* g, void* l) {
  __builtin_amdgcn_global_load_lds((const __attribute__((address_space(1))) void*)g,
                                   (__attribute__((address_space(3))) void*)l, 16, 0, 0);
}

// ---------------- degrees / masks / denom (fp32) ----------------
__global__ void k_degrees(const float* __restrict__ adj, float* __restrict__ denom,
                          int* __restrict__ pmask, int* __restrict__ dmask) {
  int b = blockIdx.x, t = threadIdx.x;  // 128 threads
  const float* A = adj + (size_t)b * SS * SS;
  float indeg = 0.f;
  for (int s = 0; s < SS; ++s) indeg += A[s * SS + t];
  float outdeg = 0.f;
  const float4* row = (const float4*)(A + t * SS);
#pragma unroll
  for (int i = 0; i < SS / 4; ++i) { float4 v = row[i]; outdeg += v.x + v.y + v.z + v.w; }
  int idx = b * SS + t;
  denom[idx] = outdeg + 1.f;
  pmask[idx] = ((indeg + outdeg) == 0.f) ? 1 : 0;
  dmask[idx] = (indeg == 0.f) ? 1 : 0;
}

// ---------------- embedding gather -> h0 bf16 [B*S][384], cols 360..383 zero ----
__global__ void k_embed(const int* __restrict__ words, const int* __restrict__ pos,
                        const int* __restrict__ ner,
                        const float* __restrict__ emb_w, const float* __restrict__ pos_w,
                        const float* __restrict__ ner_w, bf16* __restrict__ h) {
  int tid = threadIdx.x;  // 192 threads: 180 data (2 floats each), 12 pad-zero
  int tok0 = blockIdx.x * 16;
  for (int i = 0; i < 16; ++i) {
    int tok = tok0 + i;
    if (tid < 180) {
      int c = tid * 2;
      float2 v;
      if (c < 300)      v = *(const float2*)(emb_w + (size_t)words[tok] * 300 + c);
      else if (c < 330) v = *(const float2*)(pos_w + (size_t)pos[tok] * 30 + (c - 300));
      else              v = *(const float2*)(ner_w + (size_t)ner[tok] * 30 + (c - 330));
      union { bf16 b[2]; uint32_t u; } cvt;
      cvt.b[0] = (bf16)v.x; cvt.b[1] = (bf16)v.y;
      *(uint32_t*)(h + (size_t)tok * DINP + c) = cvt.u;
    } else {
      int c = 360 + (tid - 180) * 2;
      *(uint32_t*)(h + (size_t)tok * DINP + c) = 0u;
    }
  }
}

// ---------------- W [K][N] fp32 -> WT bf16 [RP][SP] zero-padded ----------------
__global__ void k_prepw(const float* __restrict__ W, int K, int N,
                        bf16* __restrict__ WT, int RP, int SP) {
  int idx = blockIdx.x * 256 + threadIdx.x;
  if (idx >= RP * SP) return;
  int r = idx / SP, c = idx % SP;
  float v = (r < N && c < K) ? W[(size_t)c * N + r] : 0.f;
  WT[(size_t)r * SP + c] = (bf16)v;
}

// ---------------- W [K][N] fp32 -> WT bf16 [NP][KP] zero-padded (MLP weights) ----
__global__ void k_prepwb(const float* __restrict__ W, int K, int N,
                         bf16* __restrict__ WT, int KP, int NP) {
  int idx = blockIdx.x * 256 + threadIdx.x;
  if (idx >= NP * KP) return;
  int n = idx / KP, k = idx - n * KP;
  float v = (n < N && k < K) ? W[(size_t)k * N + n] : 0.f;
  WT[(size_t)n * KP + k] = (bf16)v;
}

// ---------------- query = pool_max(h0) ; qa = attn_w @ query ----------------
__global__ void k_query_qa(const bf16* __restrict__ h, const int* __restrict__ pmask,
                           const float* __restrict__ attn_w, float* __restrict__ qa) {
  __shared__ float q[DIN];
  __shared__ int pm[SS];
  int b = blockIdx.x, tid = threadIdx.x;  // 384 threads
  if (tid < SS) pm[tid] = pmask[b * SS + tid];
  __syncthreads();
  if (tid < DIN) {
    float m = -INF_;
    const bf16* hb = h + (size_t)b * SS * DINP + tid;
    for (int s = 0; s < SS; ++s) { float v = (float)hb[(size_t)s * DINP]; if (!pm[s]) m = fmaxf(m, v); }
    q[tid] = m;
  }
  __syncthreads();
  if (tid < DDEPW) {
    const float* wr = attn_w + (size_t)tid * DIN;
    float acc = 0.f;
    for (int e = 0; e < DIN; ++e) acc += wr[e] * q[e];
    qa[b * SS + tid] = acc;
  }
}

// ---------------- scores -> softmax -> weights (fp32) ----------------
__global__ void k_weights(const int* __restrict__ deprel, const float* __restrict__ dep_w,
                          const int* __restrict__ dmask, const float* __restrict__ qa,
                          float* __restrict__ wts) {
  __shared__ float qs[DDEPW];
  __shared__ float red[SS];
  int b = blockIdx.x, s = threadIdx.x;  // 128 threads
  if (s < DDEPW) qs[s] = qa[b * SS + s];
  __syncthreads();
  float score;
  if (dmask[b * SS + s]) score = NEG_;
  else {
    const float* dr = dep_w + (size_t)deprel[b * SS + s] * DDEPW;
    float acc = 0.f;
    for (int d = 0; d < DDEPW; ++d) acc += dr[d] * qs[d];
    score = acc;
  }
  red[s] = score; __syncthreads();
  for (int off = 64; off > 0; off >>= 1) { if (s < off) red[s] = fmaxf(red[s], red[s + off]); __syncthreads(); }
  float mx = red[0]; __syncthreads();
  float ex = expf(score - mx);
  red[s] = ex; __syncthreads();
  for (int off = 64; off > 0; off >>= 1) { if (s < off) red[s] += red[s + off]; __syncthreads(); }
  wts[b * SS + s] = ex / red[0];
}

// ---------------- amat bf16: a[s,t] = adj[s,t]*w[s] + adj[t,s]*w[t] ----------------
__global__ void k_symmetrize(const float* __restrict__ adj, const float* __restrict__ wts,
                             bf16* __restrict__ amat) {
  __shared__ float tile[SS * SS];  // 64 KiB, skewed: (s,t) at [s*128 + ((t+s)&127)]
  int b = blockIdx.x, tid = threadIdx.x;  // 256 threads
  const float* Ab = adj + (size_t)b * SS * SS;
  bf16* ab = amat + (size_t)b * SS * SS;
#pragma unroll 4
  for (int i = 0; i < 64; ++i) {
    int idx = i * 256 + tid;
    int s_ = idx >> 7, t_ = idx & 127;
    tile[(s_ << 7) + ((t_ + s_) & 127)] = Ab[idx];
  }
  __syncthreads();
  const float* wb = wts + b * SS;
#pragma unroll 4
  for (int i = 0; i < 64; ++i) {
    int idx = i * 256 + tid;
    int s_ = idx >> 7, t_ = idx & 127;
    float v = tile[(s_ << 7) + ((t_ + s_) & 127)] * wb[s_]
            + tile[(t_ << 7) + ((s_ + t_) & 127)] * wb[t_];
    ab[idx] = (bf16)v;
  }
}

// ---------------- dense MFMA: g = X @ Y^T (no epilogue), bf16 out ----------------
// BM=128 BN=160 BK=64; global_load_lds(16B) into XOR-swizzled linear LDS.
// LDS: elem(row, kg of 8) at row*64 + ((kg ^ (row&7))*8)   [128B rows]
__global__ __launch_bounds__(256, 4) void k_dense(
    const bf16* __restrict__ X, const bf16* __restrict__ Y,
    bf16* __restrict__ Cout, int K, int SC) {
  __shared__ __align__(16) bf16 As[128 * 64];  // 16 KB
  __shared__ __align__(16) bf16 Bs[160 * 64];  // 20 KB
  int tid = threadIdx.x;
  int mblk = blockIdx.y * 128, nblk = blockIdx.x * 160;
  int wid = tid >> 6, lane = tid & 63;
  int wm = (wid >> 1) * 64, wn = (wid & 1) * 80;
  int lr = lane & 15, lg = lane >> 4;
  int srow = tid >> 3, slot = tid & 7;
  f32x4 acc[4][5];
#pragma unroll
  for (int i = 0; i < 4; ++i)
#pragma unroll
    for (int j = 0; j < 5; ++j) acc[i][j] = (f32x4){0.f, 0.f, 0.f, 0.f};

  for (int k0 = 0; k0 < K; k0 += 64) {
    __syncthreads();
#pragma unroll
    for (int it = 0; it < 4; ++it) {
      int row = it * 32 + srow;
      int kg = slot ^ (row & 7);
      gload16(&X[(size_t)(mblk + row) * K + k0 + kg * 8], &As[(it * 256 + wid * 64) * 8]);
    }
#pragma unroll
    for (int it = 0; it < 5; ++it) {
      int row = it * 32 + srow;
      int kg = slot ^ (row & 7);
      gload16(&Y[(size_t)(nblk + row) * K + k0 + kg * 8], &Bs[(it * 256 + wid * 64) * 8]);
    }
    __syncthreads();
#pragma unroll
    for (int kk = 0; kk < 2; ++kk) {
      bf16x8 a[4], b[5];
#pragma unroll
      for (int mi = 0; mi < 4; ++mi) {
        int r = wm + mi * 16 + lr;
        a[mi] = *(const bf16x8*)&As[r * 64 + (((kk * 4 + lg) ^ (lr & 7)) * 8)];
      }
#pragma unroll
      for (int nf = 0; nf < 5; ++nf) {
        int r = wn + nf * 16 + lr;
        b[nf] = *(const bf16x8*)&Bs[r * 64 + (((kk * 4 + lg) ^ (lr & 7)) * 8)];
      }
#pragma unroll
      for (int mi = 0; mi < 4; ++mi)
#pragma unroll
        for (int nf = 0; nf < 5; ++nf)
          acc[mi][nf] = __builtin_amdgcn_mfma_f32_16x16x32_bf16(a[mi], b[nf], acc[mi][nf], 0, 0, 0);
    }
  }
#pragma unroll
  for (int mi = 0; mi < 4; ++mi) {
    int m0 = mblk + wm + mi * 16 + lg * 4;
#pragma unroll
    for (int nf = 0; nf < 5; ++nf) {
      int n = nblk + wn + nf * 16 + lr;
#pragma unroll
      for (int i = 0; i < 4; ++i)
        Cout[(size_t)(m0 + i) * SC + n] = (bf16)acc[mi][nf][i];
    }
  }
}

// ---------------- GCN combine: h' = relu((a@g + g + 2b)/denom) ----------------
// Barrier-free K=128 fully-resident: amat via gload16+swizzle (Xs), g-tile
// reg-stage-transposed into Ys[n][k] (XOR-swizzled) so B-frags are ds_read_b128.
// Epilogue reads +g from Ys (no global re-read). Grid (SGP/160, NB).
template<bool F32OUT>
__global__ __launch_bounds__(256) void k_ah(
    const bf16* __restrict__ amat, const bf16* __restrict__ g,
    const float* __restrict__ bias, const float* __restrict__ denom,
    void* __restrict__ Hout, int SG, int NVALID, int SC) {
  __shared__ __align__(16) bf16 Xs[128 * 128];  // amat[m][k], kg ^= (m&15)
  __shared__ __align__(16) bf16 Ys[160 * 128];  // gT[n][k],  kg ^= (n&15)
  int z = blockIdx.y;
  int nblk = blockIdx.x * 160;
  int tid = threadIdx.x;
  const bf16* Az = amat + (size_t)z * SS * SS;
  const bf16* gz = g + (size_t)z * SS * SG;
  {  // A: async 16B loads, pre-swizzled source
    int wv = tid >> 6;
#pragma unroll
    for (int it = 0; it < 8; ++it) {
      int j = it * 256 + tid;
      int row = j >> 4, slot = j & 15;
      int kg = slot ^ (row & 15);
      gload16(&Az[(size_t)row * SS + kg * 8], &Xs[(it * 256 + wv * 64) * 8]);
    }
  }
  {  // B: read g rows coalesced (b128), scatter-transpose into Ys
    int m = tid & 127, half = tid >> 7;
    int mg = m >> 3, ml = m & 7;
#pragma unroll
    for (int it = 0; it < 10; ++it) {
      int n0 = (it * 2 + half) * 8;  // [0,160)
      bf16x8 v = *(const bf16x8*)&gz[(size_t)m * SG + nblk + n0];
#pragma unroll
      for (int j = 0; j < 8; ++j) {
        int n = n0 + j;
        Ys[n * 128 + ((mg ^ (n & 15)) * 8) + ml] = v[j];
      }
    }
  }
  __syncthreads();

  int wid = tid >> 6, lane = tid & 63;
  int wm = (wid >> 1) * 64, wn = (wid & 1) * 80;
  int lr = lane & 15, lg = lane >> 4;
  f32x4 acc[4][5];
#pragma unroll
  for (int i = 0; i < 4; ++i)
#pragma unroll
    for (int j = 0; j < 5; ++j) acc[i][j] = (f32x4){0.f, 0.f, 0.f, 0.f};

#pragma unroll
  for (int ks = 0; ks < 4; ++ks) {
    int kg = ks * 4 + lg;
    bf16x8 a[4], b[5];
#pragma unroll
    for (int mi = 0; mi < 4; ++mi) {
      int r = wm + mi * 16 + lr;
      a[mi] = *(const bf16x8*)&Xs[r * 128 + ((kg ^ (r & 15)) * 8)];
    }
#pragma unroll
    for (int nf = 0; nf < 5; ++nf) {
      int n = wn + nf * 16 + lr;
      b[nf] = *(const bf16x8*)&Ys[n * 128 + ((kg ^ (n & 15)) * 8)];
    }
#pragma unroll
    for (int mi = 0; mi < 4; ++mi)
#pragma unroll
      for (int nf = 0; nf < 5; ++nf)
        acc[mi][nf] = __builtin_amdgcn_mfma_f32_16x16x32_bf16(a[mi], b[nf], acc[mi][nf], 0, 0, 0);
  }

#pragma unroll
  for (int mi = 0; mi < 4; ++mi) {
    int m0 = wm + mi * 16 + lg * 4;
    float dn[4];
#pragma unroll
    for (int i = 0; i < 4; ++i) dn[i] = denom[z * SS + m0 + i];
#pragma unroll
    for (int nf = 0; nf < 5; ++nf) {
      int n = wn + nf * 16 + lr;   // tile-local
      int ng = nblk + n;           // global col
      float bs = (ng < DHID) ? 2.f * bias[ng] : 0.f;
#pragma unroll
      for (int i = 0; i < 4; ++i) {
        int m = m0 + i;
        float gv = (float)Ys[n * 128 + (((m >> 3) ^ (n & 15)) * 8) + (m & 7)];
        float v = fmaxf((acc[mi][nf][i] + gv + bs) / dn[i], 0.f);
        if (F32OUT) {
          if (ng < NVALID) ((float*)Hout)[((size_t)z * SS + m) * SC + ng] = v;
        } else {
          ((bf16*)Hout)[((size_t)z * SS + m) * SC + ng] = (bf16)v;
        }
      }
    }
  }
}

// ---------------- MLP via wave-per-16x16-tile MFMA (no LDS, no barriers) --------
template<bool RELU, bool BF16OUT, int KP, int NP, int NVALID>
__global__ __launch_bounds__(256) void k_mlp_mfma(
    const bf16* __restrict__ A, const bf16* __restrict__ BT,
    const float* __restrict__ bias, void* __restrict__ C, int M, int SC) {
  constexpr int NT = NP / 16;
  int wid = threadIdx.x >> 6, lane = threadIdx.x & 63;
  int wti = blockIdx.x * 4 + wid;
  int mt = wti / NT, nt = wti - mt * NT;
  if (mt * 16 >= M) return;
  int lr = lane & 15, lg = lane >> 4;
  const bf16* Ap = A + (size_t)(mt * 16 + lr) * KP + lg * 8;
  const bf16* Bp = BT + (size_t)(nt * 16 + lr) * KP + lg * 8;
  f32x4 acc = (f32x4){0.f, 0.f, 0.f, 0.f};
#pragma unroll
  for (int k0 = 0; k0 < KP; k0 += 32) {
    bf16x8 a = *(const bf16x8*)(Ap + k0);
    bf16x8 b = *(const bf16x8*)(Bp + k0);
    acc = __builtin_amdgcn_mfma_f32_16x16x32_bf16(a, b, acc, 0, 0, 0);
  }
  int n = nt * 16 + lr;
  int m0 = mt * 16 + lg * 4;
  float bs = (n < NVALID) ? bias[n] : 0.f;
  if (BF16OUT) {
#pragma unroll
    for (int i = 0; i < 4; ++i) {
      float v = 0.f;
      if (n < NVALID) { v = acc[i] + bs; if (RELU) v = fmaxf(v, 0.f); }
      ((bf16*)C)[(size_t)(m0 + i) * SC + n] = (bf16)v;
    }
  } else {
    if (n < NVALID) {
#pragma unroll
      for (int i = 0; i < 4; ++i) {
        float v = acc[i] + bs;
        if (RELU) v = fmaxf(v, 0.f);
        ((float*)C)[(size_t)(m0 + i) * SC + n] = v;
      }
    }
  }
}

// ---------------- final 3-way masked max pool -> bf16 cat [B][928] + fp32 h_out --
__global__ void k_pool(const float* __restrict__ h, const int* __restrict__ pmask,
                       const int* __restrict__ subj_pos, const int* __restrict__ obj_pos,
                       bf16* __restrict__ catb, float* __restrict__ hout) {
  __shared__ int pm[SS], sm[SS], om[SS];
  int b = blockIdx.x, e = threadIdx.x;  // 384 threads
  if (e < SS) {
    pm[e] = pmask[b * SS + e];
    sm[e] = (subj_pos[b * SS + e] != 0) ? 1 : 0;
    om[e] = (obj_pos[b * SS + e] != 0) ? 1 : 0;
  }
  __syncthreads();
  if (e < DHID) {
    const float* hb = h + (size_t)b * SS * DHID + e;
    float mh = -INF_, ms = -INF_, mo = -INF_;
    for (int s = 0; s < SS; ++s) {
      float v = hb[(size_t)s * DHID];
      if (!pm[s]) mh = fmaxf(mh, v);
      if (!sm[s]) ms = fmaxf(ms, v);
      if (!om[s]) mo = fmaxf(mo, v);
    }
    catb[(size_t)b * KCAT + e] = (bf16)mh;
    catb[(size_t)b * KCAT + 300 + e] = (bf16)ms;
    catb[(size_t)b * KCAT + 600 + e] = (bf16)mo;
    hout[(size_t)b * DHID + e] = mh;
  } else if (e < DHID + (KCAT - 3 * DHID)) {  // zero cols 900..927
    catb[(size_t)b * KCAT + 600 + e] = (bf16)0.f;
  }
}

extern "C" void kernel_launch(void* const* d_in, const int* in_sizes, int n_in,
                              void* d_out, int out_size, void* d_ws, size_t ws_size,
                              hipStream_t stream) {
  const int* words = (const int*)d_in[0];
  const int* pos = (const int*)d_in[1];
  const int* ner = (const int*)d_in[2];
  const int* deprel = (const int*)d_in[3];
  const int* subj_pos = (const int*)d_in[4];
  const int* obj_pos = (const int*)d_in[5];
  const float* adj = (const float*)d_in[6];
  const float* emb_w = (const float*)d_in[7];
  const float* pos_w = (const float*)d_in[8];
  const float* ner_w = (const float*)d_in[9];
  const float* dep_w = (const float*)d_in[10];
  const float* attn_w = (const float*)d_in[11];
  const float* W0 = (const float*)d_in[12];
  const float* b0 = (const float*)d_in[13];
  const float* W1 = (const float*)d_in[14];
  const float* b1 = (const float*)d_in[15];
  const float* mlp0_w = (const float*)d_in[16];
  const float* mlp0_b = (const float*)d_in[17];
  const float* mlp1_w = (const float*)d_in[18];
  const float* mlp1_b = (const float*)d_in[19];
  const float* cls_w = (const float*)d_in[20];
  const float* cls_b = (const float*)d_in[21];
  float* out = (float*)d_out;

  // -------- workspace carve (~140 MB), liveness reuse --------
  // bufA: h0 [65536][384] bf16 -> h1 [65536][320] bf16 -> h2f [65536][300] f32
  // bufB: g  [65536][320] bf16 (layer-1 then layer-2)
  char* w = (char*)d_ws;
  bf16* h0 = (bf16*)w;
  bf16* h1 = (bf16*)w;
  float* h2f = (float*)w;
  w += 78643200;
  bf16* g = (bf16*)w; w += 41943040;      // [65536][320]
  bf16* amat = (bf16*)w; w += 16777216;   // [512][128][128]
  bf16* W0T = (bf16*)w; w += 294912;      // [384][384]
  bf16* W1T = (bf16*)w; w += 204800;      // [320][320]
  float* denom = (float*)w; w += 262144;
  int* pmask = (int*)w; w += 262144;
  int* dmask = (int*)w; w += 262144;
  float* qa = (float*)w; w += 262144;
  float* wts = (float*)w; w += 262144;
  bf16* catb = (bf16*)w; w += 950272;     // [512][928] bf16
  bf16* m0b = (bf16*)w; w += 327680;      // [512][320] bf16
  bf16* m1b = (bf16*)w; w += 327680;      // [512][320] bf16
  bf16* M0T = (bf16*)w; w += 593920;      // [320][928] bf16
  bf16* M1T = (bf16*)w; w += 204800;      // [320][320] bf16
  bf16* CLT = (bf16*)w; w += 30720;       // [48][320] bf16

  k_prepw<<<(384 * 384 + 255) / 256, 256, 0, stream>>>(W0, DIN, DHID, W0T, DINP, DINP);
  k_prepw<<<(320 * 320 + 255) / 256, 256, 0, stream>>>(W1, DHID, DHID, W1T, DHP, DHP);
  k_prepwb<<<(320 * 928 + 255) / 256, 256, 0, stream>>>(mlp0_w, 900, DHID, M0T, KCAT, DHP);
  k_prepwb<<<(320 * 320 + 255) / 256, 256, 0, stream>>>(mlp1_w, DHID, DHID, M1T, DHP, DHP);
  k_prepwb<<<(48 * 320 + 255) / 256, 256, 0, stream>>>(cls_w, DHID, NCLS, CLT, DHP, 48);
  k_degrees<<<NB, SS, 0, stream>>>(adj, denom, pmask, dmask);
  k_embed<<<(NB * SS) / 16, 192, 0, stream>>>(words, pos, ner, emb_w, pos_w, ner_w, h0);
  k_query_qa<<<NB, 384, 0, stream>>>(h0, pmask, attn_w, qa);
  k_weights<<<NB, SS, 0, stream>>>(deprel, dep_w, dmask, qa, wts);
  k_symmetrize<<<NB, 256, 0, stream>>>(adj, wts, amat);

  // Layer 1 (reordered): g = h0@W0 ; h1 = relu((a@g + g + 2*b0)/denom)
  k_dense<<<dim3(2, NB), 256, 0, stream>>>(h0, W0T, g, DINP, DHP);
  k_ah<false><<<dim3(2, NB), 256, 0, stream>>>(amat, g, b0, denom, h1, DHP, DHP, DHP);
  // Layer 2: g = h1@W1 ; h2 = relu((a@g + g + 2*b1)/denom) -> fp32 [65536][300]
  k_dense<<<dim3(2, NB), 256, 0, stream>>>(h1, W1T, g, DHP, DHP);
  k_ah<true><<<dim3(2, NB), 256, 0, stream>>>(amat, g, b1, denom, h2f, DHP, DHID, DHID);

  // pools -> catb bf16 [512][928] (zero-padded); h_out fp32 -> out + NB*NCLS
  k_pool<<<NB, 384, 0, stream>>>(h2f, pmask, subj_pos, obj_pos, catb, out + NB * NCLS);

  // MLP + classifier: wave-per-tile MFMA
  k_mlp_mfma<true, true, KCAT, DHP, DHID><<<(512 / 16) * (DHP / 16) / 4, 256, 0, stream>>>(
      catb, M0T, mlp0_b, m0b, NB, DHP);
  k_mlp_mfma<true, true, DHP, DHP, DHID><<<(512 / 16) * (DHP / 16) / 4, 256, 0, stream>>>(
      m0b, M1T, mlp1_b, m1b, NB, DHP);
  k_mlp_mfma<false, false, DHP, 48, NCLS><<<(512 / 16) * (48 / 16) / 4, 256, 0, stream>>>(
      m1b, CLT, cls_b, out, NB, NCLS);
}